// Round 9
// baseline (887.441 us; speedup 1.0000x reference)
//
#include <hip/hip_runtime.h>
#include <hip/hip_bf16.h>
#include <math.h>

#define NNODES  50000
#define NEDGES  200000
#define NTOT    250000      // E + N self loops
#define EMB     300
#define LDK     320         // padded K stride (bf16 h / mh / weights)
#define MPAD    50048       // 391 * 128 (GEMM M padding)
#define NLAYERS 5
#define NSCAN   49          // ceil(NNODES / 1024)

struct EdgeRec { int r; float c0, c1; };

typedef __attribute__((ext_vector_type(8))) short short8;
typedef __attribute__((ext_vector_type(4))) short short4v;
typedef __attribute__((ext_vector_type(4))) float floatx4;

__device__ inline void gll16(const void* g, void* s) {
    __builtin_amdgcn_global_load_lds((const __attribute__((address_space(1))) unsigned*)g,
                                     (__attribute__((address_space(3))) unsigned*)s, 16, 0, 0);
}

// ---------------- merged transposes for readout weights (head path only) ----------------
__global__ void k_trall(const float* __restrict__ wv, const float* __restrict__ lg_w,
                        const float* __restrict__ ph1_w, const float* __restrict__ me1_w,
                        float* __restrict__ wvT, float* __restrict__ lgwT,
                        float* __restrict__ ph1wT, float* __restrict__ me1wT) {
    int idx = blockIdx.x * 256 + threadIdx.x;
    if (idx < 76800) { int r = idx / 300, c = idx % 300; wvT[c * 256 + r] = wv[idx]; return; }
    idx -= 76800;
    if (idx < 76800) { int r = idx / 300, c = idx % 300; lgwT[c * 256 + r] = lg_w[idx]; return; }
    idx -= 76800;
    if (idx < 131072) { int r = idx / 256, c = idx % 256; ph1wT[c * 512 + r] = ph1_w[idx]; return; }
    idx -= 131072;
    if (idx < 5100) { int r = idx / 17, c = idx % 17; me1wT[c * 300 + r] = me1_w[idx]; }
}

// ---------------- weight convert: wb[l][320][320] = bf16(mlp_w[l][300][300]) zero-padded ----------------
__global__ void k_cvt(const float* __restrict__ w, __hip_bfloat16* __restrict__ wb) {
    int idx = blockIdx.x * 256 + threadIdx.x;
    if (idx >= 5 * 320 * 320) return;
    int l = idx / 102400, r = idx % 102400, n = r / 320, k = r % 320;
    float v = (n < 300 && k < 300) ? w[l * 90000 + n * 300 + k] : 0.f;
    wb[idx] = __float2bfloat16(v);
}

// ---------------- metal-path weight packs: wcat[512][320] = [wq; ml_w], wkTb[320][256] = wk^T ----------------
__global__ void k_cvt2(const float* __restrict__ wq, const float* __restrict__ ml_w,
                       const float* __restrict__ wk,
                       __hip_bfloat16* __restrict__ wcat, __hip_bfloat16* __restrict__ wkTb) {
    int idx = blockIdx.x * 256 + threadIdx.x;
    if (idx < 512 * 320) {
        int r = idx / 320, k = idx % 320;
        float v = 0.f;
        if (k < 300) v = (r < 256) ? wq[r * 300 + k] : ml_w[(r - 256) * 300 + k];
        wcat[idx] = __float2bfloat16(v);
        return;
    }
    idx -= 512 * 320;
    if (idx < 320 * 256) {
        int c = idx / 256, j = idx % 256;
        float v = (c < 300) ? wk[j * 300 + c] : 0.f;
        wkTb[idx] = __float2bfloat16(v);
    }
}

// ---------------- mf = me1b + me2[mt] + mfeat @ me1wT, bf16 [1024,320] (pads pre-zeroed) ----------------
__global__ __launch_bounds__(256) void k_mf(const int* __restrict__ mt, const float* __restrict__ mfeat,
                                            const float* __restrict__ me1wT, const float* __restrict__ me1b,
                                            const float* __restrict__ me2,
                                            __hip_bfloat16* __restrict__ mfb) {
    int idx = blockIdx.x * 256 + threadIdx.x;
    if (idx >= 1000 * 300) return;
    int g = idx / 300, c = idx % 300;
    float v = me1b[c] + me2[(size_t)mt[g] * 300 + c];
    #pragma unroll
    for (int k = 0; k < 17; ++k) v += mfeat[g * 17 + k] * me1wT[k * 300 + c];
    mfb[(size_t)g * 320 + c] = __float2bfloat16(v);
}

// ---------------- generic 128x64 MFMA GEMM for metal path ----------------
__global__ __launch_bounds__(256) void k_mm(const __hip_bfloat16* __restrict__ A, int lda,
                                            const __hip_bfloat16* __restrict__ B, int ldb,
                                            int K, int mode,
                                            const float* __restrict__ mlb,
                                            __hip_bfloat16* __restrict__ qb,
                                            float* __restrict__ metal2,
                                            float* __restrict__ qkout) {
    __shared__ __hip_bfloat16 As[128 * 32];
    __shared__ __hip_bfloat16 Bs[64 * 32];
    int tid = threadIdx.x, lane = tid & 63, w = tid >> 6;
    int row0 = blockIdx.x * 128, col0 = blockIdx.y * 64;

    floatx4 acc[2][4];
    #pragma unroll
    for (int i = 0; i < 2; ++i)
        #pragma unroll
        for (int j = 0; j < 4; ++j) acc[i][j] = (floatx4){0.f, 0.f, 0.f, 0.f};

    const __hip_bfloat16* ga0 = A + (size_t)(row0 + w * 32 + (lane >> 2)) * lda + (lane & 3) * 8;
    const __hip_bfloat16* ga1 = ga0 + (size_t)16 * lda;
    const __hip_bfloat16* gb  = B + (size_t)(col0 + w * 16 + (lane >> 2)) * ldb + (lane & 3) * 8;
    __hip_bfloat16* sa0 = &As[(w * 32) * 32];
    __hip_bfloat16* sa1 = &As[(w * 32 + 16) * 32];
    __hip_bfloat16* sb  = &Bs[(w * 16) * 32];

    int m15 = lane & 15, kof = (lane >> 4) * 8;

    for (int k0 = 0; k0 < K; k0 += 32) {
        __syncthreads();
        gll16(ga0 + k0, sa0);
        gll16(ga1 + k0, sa1);
        gll16(gb  + k0, sb);
        __syncthreads();

        short8 a[2], b[4];
        a[0] = *(const short8*)&As[(w * 32 +      m15) * 32 + kof];
        a[1] = *(const short8*)&As[(w * 32 + 16 + m15) * 32 + kof];
        #pragma unroll
        for (int nt = 0; nt < 4; ++nt)
            b[nt] = *(const short8*)&Bs[(nt * 16 + m15) * 32 + kof];

        #pragma unroll
        for (int mt = 0; mt < 2; ++mt)
            #pragma unroll
            for (int nt = 0; nt < 4; ++nt)
                acc[mt][nt] = __builtin_amdgcn_mfma_f32_16x16x32_bf16(a[mt], b[nt], acc[mt][nt], 0, 0, 0);
    }

    int rbase = row0 + w * 32 + (lane >> 4) * 4;
    #pragma unroll
    for (int mt = 0; mt < 2; ++mt)
        #pragma unroll
        for (int i = 0; i < 4; ++i) {
            int gr = rbase + mt * 16 + i;
            #pragma unroll
            for (int nt = 0; nt < 4; ++nt) {
                int gc = col0 + nt * 16 + m15;
                float v = acc[mt][nt][i];
                if (mode == 0) {
                    if (gc < 256) qb[(size_t)gr * 256 + gc] = __float2bfloat16(v);
                    else if (gr < 1000) metal2[(size_t)gr * 256 + (gc - 256)] = fmaxf(v + mlb[gc - 256], 0.f);
                } else {
                    if (gc < 300 && gr < 1000) qkout[(size_t)gr * 320 + gc] = v;
                }
            }
        }
}

// ---------------- node init: h = bf16(x_emb[x_type] + x_feat @ x_weight), 8 cols/thread ----------------
__global__ __launch_bounds__(256) void k_init(const int* __restrict__ xt,
                                              const float* __restrict__ xf,
                                              const float* __restrict__ xemb,
                                              const float* __restrict__ xw,
                                              __hip_bfloat16* __restrict__ h) {
    int gid = blockIdx.x * 256 + threadIdx.x;
    if (gid >= NNODES * 38) return;
    int n = gid / 38, c = (gid % 38) * 8;     // c in {0,8,...,296}
    bool full = (c <= 292);
    const float* er = xemb + (size_t)xt[n] * 300 + c;
    float v[8];
    float4 e0 = *(const float4*)er;
    v[0] = e0.x; v[1] = e0.y; v[2] = e0.z; v[3] = e0.w;
    if (full) { float4 e1 = *(const float4*)(er + 4); v[4] = e1.x; v[5] = e1.y; v[6] = e1.z; v[7] = e1.w; }
    else      { v[4] = v[5] = v[6] = v[7] = 0.f; }
    float fs[16];
    const float4* xf4 = (const float4*)(xf + n * 16);
    #pragma unroll
    for (int q = 0; q < 4; ++q) {
        float4 t = xf4[q];
        fs[4 * q] = t.x; fs[4 * q + 1] = t.y; fs[4 * q + 2] = t.z; fs[4 * q + 3] = t.w;
    }
    #pragma unroll
    for (int k = 0; k < 16; ++k) {
        const float* wr = xw + k * 300 + c;
        float4 w0 = *(const float4*)wr;
        v[0] += fs[k] * w0.x; v[1] += fs[k] * w0.y; v[2] += fs[k] * w0.z; v[3] += fs[k] * w0.w;
        if (full) {
            float4 w1 = *(const float4*)(wr + 4);
            v[4] += fs[k] * w1.x; v[5] += fs[k] * w1.y; v[6] += fs[k] * w1.z; v[7] += fs[k] * w1.w;
        }
    }
    alignas(16) __hip_bfloat16 ob[8];
    #pragma unroll
    for (int i = 0; i < 8; ++i) ob[i] = __float2bfloat16(v[i]);
    __hip_bfloat16* hp = h + (size_t)n * LDK + c;
    if (full) *(short8*)hp  = *(const short8*)ob;
    else      *(short4v*)hp = *(const short4v*)ob;
}

// ---------------- CSR build ----------------
__global__ void k_count(const int* __restrict__ ei, int* __restrict__ cnt) {
    int e = blockIdx.x * blockDim.x + threadIdx.x;
    if (e >= NTOT) return;
    int c = (e < NEDGES) ? ei[NEDGES + e] : (e - NEDGES);
    atomicAdd(&cnt[c], 1);
}

__global__ __launch_bounds__(1024) void k_scan1(const int* __restrict__ cnt, int* __restrict__ off,
                                                int* __restrict__ bsum) {
    int tid = threadIdx.x;
    int gid = blockIdx.x * 1024 + tid;
    int lane = tid & 63, wv = tid >> 6;
    int v = (gid < NNODES) ? cnt[gid] : 0;
    int x = v;
    #pragma unroll
    for (int s = 1; s < 64; s <<= 1) {
        int t = __shfl_up(x, s, 64);
        if (lane >= s) x += t;
    }
    __shared__ int wsum[16];
    if (lane == 63) wsum[wv] = x;
    __syncthreads();
    if (wv == 0) {
        int w = (lane < 16) ? wsum[lane] : 0;
        #pragma unroll
        for (int s = 1; s < 16; s <<= 1) {
            int t = __shfl_up(w, s, 64);
            if (lane >= s) w += t;
        }
        if (lane < 16) wsum[lane] = w;
    }
    __syncthreads();
    int base = (wv > 0) ? wsum[wv - 1] : 0;
    int incl = x + base;
    if (gid < NNODES) off[gid] = incl - v;
    if (tid == 1023) bsum[blockIdx.x] = incl;
}

__global__ __launch_bounds__(64) void k_scan2(int* __restrict__ bsum) {
    int lane = threadIdx.x;
    int v = (lane < NSCAN) ? bsum[lane] : 0;
    int x = v;
    #pragma unroll
    for (int s = 1; s < 64; s <<= 1) {
        int t = __shfl_up(x, s, 64);
        if (lane >= s) x += t;
    }
    if (lane < NSCAN) bsum[lane] = x - v;
}

__global__ __launch_bounds__(1024) void k_scan3(int* __restrict__ off, const int* __restrict__ bsum) {
    int gid = blockIdx.x * 1024 + threadIdx.x;
    if (gid < NNODES) off[gid] += bsum[blockIdx.x];
    if (gid == 0) off[NNODES] = NTOT;
}

__global__ void k_fill(const int* __restrict__ ei, const float* __restrict__ ea,
                       const int* __restrict__ off, int* __restrict__ cur,
                       EdgeRec* __restrict__ pack) {
    int e = blockIdx.x * blockDim.x + threadIdx.x;
    if (e >= NTOT) return;
    int r, c; float c0, c1;
    if (e < NEDGES) { r = ei[e]; c = ei[NEDGES + e]; c0 = ea[2 * e]; c1 = ea[2 * e + 1]; }
    else            { r = c = e - NEDGES; c0 = 0.f; c1 = 4.f; }
    int p = atomicAdd(&cur[c], 1);
    EdgeRec rec; rec.r = r; rec.c0 = c0; rec.c1 = c1;
    pack[off[c] + p] = rec;
}

// ---------------- per-layer precompute, all layers in one launch ----------------
__global__ __launch_bounds__(64) void k_prep(const float* __restrict__ mlp_w, const float* __restrict__ ew1,
                                             const float* __restrict__ mlp_b, const float* __restrict__ bn_g,
                                             const float* __restrict__ bn_b, const float* __restrict__ bn_rm,
                                             const float* __restrict__ bn_rv, float* __restrict__ prm) {
    int j = blockIdx.x, l = blockIdx.y;
    int lane = threadIdx.x;
    const float* W  = mlp_w + (size_t)l * 90000 + (size_t)j * 300;
    const float* ew = ew1 + l * 600;
    float a0 = 0.f, a1 = 0.f;
    #pragma unroll
    for (int i = 0; i < 5; ++i) {
        int k = lane + i * 64;
        if (k < 300) {
            float w = W[k];
            a0 += w * ew[k];
            a1 += w * ew[300 + k];
        }
    }
    #pragma unroll
    for (int s = 32; s > 0; s >>= 1) { a0 += __shfl_xor(a0, s, 64); a1 += __shfl_xor(a1, s, 64); }
    if (lane == 0) {
        float* p = prm + l * 1520;
        p[j] = a0;
        p[304 + j] = a1;
        p[608 + j] = mlp_b[l * 300 + j];
        float sc = bn_g[l * 300 + j] * rsqrtf(bn_rv[l * 300 + j] + 1e-5f);
        p[912 + j] = sc;
        p[1216 + j] = bn_b[l * 300 + j] - bn_rm[l * 300 + j] * sc;
    }
}

// ---------------- register-direct MFMA GEMM: wave = 32x160 strip, no LDS, no barriers ----------------
// A-frag and B-frag lane layouts are loaded straight from global: lane m=lane&15, k=(lane>>4)*8
__global__ __launch_bounds__(256) void k_gemm(const __hip_bfloat16* __restrict__ A,
                                              const __hip_bfloat16* __restrict__ B,
                                              __hip_bfloat16* __restrict__ C) {
    int tid = threadIdx.x;
    int lane = tid & 63, w = tid >> 6;
    int row0 = blockIdx.x * 128 + w * 32;
    int col0 = blockIdx.y * 160;
    int m15 = lane & 15, kof = (lane >> 4) * 8;

    floatx4 acc[2][10];
    #pragma unroll
    for (int i = 0; i < 2; ++i)
        #pragma unroll
        for (int j = 0; j < 10; ++j) acc[i][j] = (floatx4){0.f, 0.f, 0.f, 0.f};

    const __hip_bfloat16* pa0 = A + (size_t)(row0 + m15) * LDK + kof;
    const __hip_bfloat16* pa1 = pa0 + (size_t)16 * LDK;
    const __hip_bfloat16* pb  = B + (size_t)(col0 + m15) * LDK + kof;

    #pragma unroll 2
    for (int k0 = 0; k0 < LDK; k0 += 32) {
        short8 a0 = *(const short8*)(pa0 + k0);
        short8 a1 = *(const short8*)(pa1 + k0);
        short8 b[10];
        #pragma unroll
        for (int nt = 0; nt < 10; ++nt)
            b[nt] = *(const short8*)(pb + (size_t)(nt * 16) * LDK + k0);
        #pragma unroll
        for (int nt = 0; nt < 10; ++nt) {
            acc[0][nt] = __builtin_amdgcn_mfma_f32_16x16x32_bf16(a0, b[nt], acc[0][nt], 0, 0, 0);
            acc[1][nt] = __builtin_amdgcn_mfma_f32_16x16x32_bf16(a1, b[nt], acc[1][nt], 0, 0, 0);
        }
    }

    int rbase = row0 + (lane >> 4) * 4;
    #pragma unroll
    for (int mt = 0; mt < 2; ++mt)
        #pragma unroll
        for (int i = 0; i < 4; ++i) {
            long gr = rbase + mt * 16 + i;
            #pragma unroll
            for (int nt = 0; nt < 10; ++nt) {
                int gc = col0 + nt * 16 + m15;
                if (gc < 300)
                    C[gr * LDK + gc] = __float2bfloat16(acc[mt][nt][i]);
            }
        }
}

// ---------------- aggregate: wave/node, 2-edge unroll (R7 version) ----------------
__global__ __launch_bounds__(256) void k_aggr(const __hip_bfloat16* __restrict__ mh,
                                              const EdgeRec* __restrict__ pack,
                                              const int* __restrict__ off, const float* __restrict__ prm,
                                              __hip_bfloat16* __restrict__ h, int do_relu) {
    int wave = threadIdx.x >> 6;
    int lane = threadIdx.x & 63;
    int n = blockIdx.x * 4 + wave;
    if (n >= NNODES) return;
    float u0[3][2], u1[3][2], bv[3][2], sc[3][2], sh[3][2], acc[3][2];
    #pragma unroll
    for (int i = 0; i < 3; ++i) {
        int j = 2 * lane + 128 * i;
        #pragma unroll
        for (int t = 0; t < 2; ++t) {
            bool ok = (j + t) < 300;
            u0[i][t] = ok ? prm[j + t]        : 0.f;
            u1[i][t] = ok ? prm[304 + j + t]  : 0.f;
            bv[i][t] = ok ? prm[608 + j + t]  : 0.f;
            sc[i][t] = ok ? prm[912 + j + t]  : 0.f;
            sh[i][t] = ok ? prm[1216 + j + t] : 0.f;
            acc[i][t] = 0.f;
        }
    }
    int p0 = off[n], p1 = off[n + 1];
    int p = p0;
    for (; p + 1 < p1; p += 2) {
        EdgeRec e0 = pack[p], e1 = pack[p + 1];
        const __hip_bfloat16* b0 = mh + (size_t)e0.r * LDK;
        const __hip_bfloat16* b1 = mh + (size_t)e1.r * LDK;
        __hip_bfloat162 hv0[3], hv1[3];
        #pragma unroll
        for (int i = 0; i < 3; ++i) {
            int j = 2 * lane + 128 * i;
            if (j < 300) {
                hv0[i] = *(const __hip_bfloat162*)&b0[j];
                hv1[i] = *(const __hip_bfloat162*)&b1[j];
            }
        }
        #pragma unroll
        for (int i = 0; i < 3; ++i) {
            int j = 2 * lane + 128 * i;
            if (j < 300) {
                acc[i][0] += fmaxf(__bfloat162float(hv0[i].x) + e0.c0 * u0[i][0] + e0.c1 * u1[i][0] + bv[i][0], 0.f);
                acc[i][1] += fmaxf(__bfloat162float(hv0[i].y) + e0.c0 * u0[i][1] + e0.c1 * u1[i][1] + bv[i][1], 0.f);
                acc[i][0] += fmaxf(__bfloat162float(hv1[i].x) + e1.c0 * u0[i][0] + e1.c1 * u1[i][0] + bv[i][0], 0.f);
                acc[i][1] += fmaxf(__bfloat162float(hv1[i].y) + e1.c0 * u0[i][1] + e1.c1 * u1[i][1] + bv[i][1], 0.f);
            }
        }
    }
    if (p < p1) {
        EdgeRec e0 = pack[p];
        const __hip_bfloat16* b0 = mh + (size_t)e0.r * LDK;
        #pragma unroll
        for (int i = 0; i < 3; ++i) {
            int j = 2 * lane + 128 * i;
            if (j < 300) {
                __hip_bfloat162 hv = *(const __hip_bfloat162*)&b0[j];
                acc[i][0] += fmaxf(__bfloat162float(hv.x) + e0.c0 * u0[i][0] + e0.c1 * u1[i][0] + bv[i][0], 0.f);
                acc[i][1] += fmaxf(__bfloat162float(hv.y) + e0.c0 * u0[i][1] + e0.c1 * u1[i][1] + bv[i][1], 0.f);
            }
        }
    }
    #pragma unroll
    for (int i = 0; i < 3; ++i) {
        int j = 2 * lane + 128 * i;
        if (j < 300) {
            float v0 = acc[i][0] * sc[i][0] + sh[i][0];
            float v1 = acc[i][1] * sc[i][1] + sh[i][1];
            if (do_relu) { v0 = fmaxf(v0, 0.f); v1 = fmaxf(v1, 0.f); }
            __hip_bfloat162 o;
            o.x = __float2bfloat16(v0);
            o.y = __float2bfloat16(v1);
            *(__hip_bfloat162*)&h[(size_t)n * LDK + j] = o;
        }
    }
}

// ---------------- attention pool (qk stride 320) ----------------
__global__ __launch_bounds__(320) void k_pool(const __hip_bfloat16* __restrict__ h, const float* __restrict__ qk,
                                              float* __restrict__ wpool, float* __restrict__ mean) {
    int b = blockIdx.x;
    int tid = threadIdx.x;
    int wave = tid >> 6, lane = tid & 63;
    __shared__ float qk_s[300];
    __shared__ float sc[50];
    if (tid < 300) qk_s[tid] = qk[(size_t)b * 320 + tid];
    __syncthreads();
    for (int k = wave; k < 50; k += 5) {
        const __hip_bfloat16* hp = h + (long)(b * 50 + k) * LDK;
        float partial = 0.f;
        #pragma unroll
        for (int i = 0; i < 5; ++i) {
            int j = lane + i * 64;
            if (j < 300) partial += __bfloat162float(hp[j]) * qk_s[j];
        }
        #pragma unroll
        for (int s = 32; s > 0; s >>= 1) partial += __shfl_xor(partial, s, 64);
        if (lane == 0) sc[k] = partial * (1.f / 16.f);
    }
    __syncthreads();
    if (tid == 0) {
        float mx = sc[0];
        for (int k = 1; k < 50; ++k) mx = fmaxf(mx, sc[k]);
        float s = 0.f;
        for (int k = 0; k < 50; ++k) { float e = __expf(sc[k] - mx); sc[k] = e; s += e; }
        float inv = 1.f / s;
        for (int k = 0; k < 50; ++k) sc[k] *= inv;
    }
    __syncthreads();
    if (tid < 300) {
        float aw = 0.f, am = 0.f;
        for (int k = 0; k < 50; ++k) {
            float v = __bfloat162float(h[(long)(b * 50 + k) * LDK + tid]);
            aw += sc[k] * v;
            am += v;
        }
        wpool[b * 300 + tid] = aw;
        mean[b * 300 + tid]  = am * (1.f / 50.f);
    }
}

// ---------------- head (coalesced via transposed weights) ----------------
__global__ __launch_bounds__(512) void k_head(const float* __restrict__ wpool, const float* __restrict__ mean,
                                              const float* __restrict__ metal2,
                                              const float* __restrict__ wvT, const float* __restrict__ lgwT,
                                              const float* __restrict__ lgb,
                                              const float* __restrict__ ph1wT, const float* __restrict__ ph1b,
                                              const float* __restrict__ ph2w, const float* __restrict__ ph2b,
                                              float* __restrict__ out) {
    int b = blockIdx.x;
    int tid = threadIdx.x;
    __shared__ float wp_s[300], mn_s[300], f_s[256], red[512];
    if (tid < 300) { wp_s[tid] = wpool[b * 300 + tid]; mn_s[tid] = mean[b * 300 + tid]; }
    __syncthreads();
    if (tid < 256) {
        float att = 0.f, lg = 0.f;
        #pragma unroll 4
        for (int k = 0; k < 300; ++k) {
            att += wp_s[k] * wvT[k * 256 + tid];
            lg  += mn_s[k] * lgwT[k * 256 + tid];
        }
        lg = fmaxf(lg + lgb[tid], 0.f);
        f_s[tid] = fmaxf(att, 0.f) + metal2[b * 256 + tid] + lg;
    }
    __syncthreads();
    float a = ph1b[tid];
    #pragma unroll 8
    for (int k = 0; k < 256; ++k) a += f_s[k] * ph1wT[k * 512 + tid];
    float sp = fmaxf(a, 0.f) + log1pf(__expf(-fabsf(a)));   // stable softplus
    red[tid] = sp * ph2w[tid];
    __syncthreads();
    for (int s = 256; s > 0; s >>= 1) {
        if (tid < s) red[tid] += red[tid + s];
        __syncthreads();
    }
    if (tid == 0) out[b] = red[0] + ph2b[0];
}

extern "C" void kernel_launch(void* const* d_in, const int* in_sizes, int n_in,
                              void* d_out, int out_size, void* d_ws, size_t ws_size,
                              hipStream_t stream) {
    const int*   x_type   = (const int*)d_in[0];
    const float* x_feat   = (const float*)d_in[1];
    const int*   eindex   = (const int*)d_in[2];
    const float* eattr    = (const float*)d_in[3];
    const int*   mtype    = (const int*)d_in[4];
    const float* mfeat    = (const float*)d_in[5];
    const float* x_emb    = (const float*)d_in[6];
    const float* x_weight = (const float*)d_in[7];
    const float* ew1      = (const float*)d_in[8];
    const float* mlp_w    = (const float*)d_in[9];
    const float* mlp_b    = (const float*)d_in[10];
    const float* bn_g     = (const float*)d_in[11];
    const float* bn_b     = (const float*)d_in[12];
    const float* bn_rm    = (const float*)d_in[13];
    const float* bn_rv    = (const float*)d_in[14];
    const float* me1_w    = (const float*)d_in[15];
    const float* me1_b    = (const float*)d_in[16];
    const float* me2      = (const float*)d_in[17];
    const float* wq       = (const float*)d_in[18];
    const float* wk       = (const float*)d_in[19];
    const float* wv       = (const float*)d_in[20];
    const float* ml_w     = (const float*)d_in[21];
    const float* ml_b     = (const float*)d_in[22];
    const float* lg_w     = (const float*)d_in[23];
    const float* lg_b     = (const float*)d_in[24];
    const float* ph1_w    = (const float*)d_in[25];
    const float* ph1_b    = (const float*)d_in[26];
    const float* ph2_w    = (const float*)d_in[27];
    const float* ph2_b    = (const float*)d_in[28];

    char* ws = (char*)d_ws;
    size_t o = 0;
    auto alloc = [&](size_t bytes) -> void* {
        void* p = ws + o;
        o += (bytes + 255) & ~(size_t)255;
        return p;
    };
    __hip_bfloat16* h    = (__hip_bfloat16*)alloc((size_t)MPAD * LDK * 2);
    __hip_bfloat16* mh   = (__hip_bfloat16*)alloc((size_t)MPAD * LDK * 2);
    __hip_bfloat16* wb   = (__hip_bfloat16*)alloc((size_t)5 * 320 * 320 * 2);
    int*     cnt    = (int*)alloc((size_t)NNODES * 4);
    int*     offs   = (int*)alloc((size_t)(NNODES + 1) * 4);
    int*     cur    = (int*)alloc((size_t)NNODES * 4);
    int*     bsum   = (int*)alloc((size_t)64 * 4);
    EdgeRec* pack   = (EdgeRec*)alloc((size_t)NTOT * sizeof(EdgeRec));
    float*   prm    = (float*)alloc((size_t)NLAYERS * 1520 * 4);
    float*   metal2 = (float*)alloc((size_t)1000 * 256 * 4);
    float*   qk     = (float*)alloc((size_t)1024 * 320 * 4);
    float*   wpool  = (float*)alloc((size_t)1000 * 300 * 4);
    float*   meanp  = (float*)alloc((size_t)1000 * 300 * 4);
    float*   wvT    = (float*)alloc((size_t)300 * 256 * 4);
    float*   lgwT   = (float*)alloc((size_t)300 * 256 * 4);
    float*   ph1wT  = (float*)alloc((size_t)256 * 512 * 4);
    float*   me1wT  = (float*)alloc((size_t)17 * 300 * 4);
    __hip_bfloat16* mfb  = (__hip_bfloat16*)alloc((size_t)1024 * 320 * 2);
    __hip_bfloat16* wcat = (__hip_bfloat16*)alloc((size_t)512 * 320 * 2);
    __hip_bfloat16* wkTb = (__hip_bfloat16*)alloc((size_t)320 * 256 * 2);
    __hip_bfloat16* qb   = (__hip_bfloat16*)alloc((size_t)1024 * 256 * 2);
    (void)ws_size; (void)in_sizes; (void)n_in; (void)out_size;

    hipMemsetAsync(cnt, 0, (size_t)NNODES * 4, stream);
    hipMemsetAsync(cur, 0, (size_t)NNODES * 4, stream);
    hipMemsetAsync(mfb, 0, (size_t)1024 * 320 * 2, stream);

    k_cvt<<<(5 * 320 * 320 + 255) / 256, 256, 0, stream>>>(mlp_w, wb);
    k_cvt2<<<(512 * 320 + 320 * 256 + 255) / 256, 256, 0, stream>>>(wq, ml_w, wk, wcat, wkTb);
    k_trall<<<(289772 + 255) / 256, 256, 0, stream>>>(wv, lg_w, ph1_w, me1_w, wvT, lgwT, ph1wT, me1wT);
    k_init<<<(NNODES * 38 + 255) / 256, 256, 0, stream>>>(x_type, x_feat, x_emb, x_weight, h);
    k_count<<<(NTOT + 255) / 256, 256, 0, stream>>>(eindex, cnt);
    k_scan1<<<NSCAN, 1024, 0, stream>>>(cnt, offs, bsum);
    k_scan2<<<1, 64, 0, stream>>>(bsum);
    k_scan3<<<NSCAN, 1024, 0, stream>>>(offs, bsum);
    k_fill<<<(NTOT + 255) / 256, 256, 0, stream>>>(eindex, eattr, offs, cur, pack);
    {
        dim3 gp(300, NLAYERS);
        k_prep<<<gp, 64, 0, stream>>>(mlp_w, ew1, mlp_b, bn_g, bn_b, bn_rm, bn_rv, prm);
    }
    // metal path: mf -> {q, metal2} -> qk  (batched MFMA GEMMs)
    k_mf<<<(1000 * 300 + 255) / 256, 256, 0, stream>>>(mtype, mfeat, me1wT, me1_b, me2, mfb);
    {
        dim3 g1(8, 8);   // M=1024, N=512, K=320
        k_mm<<<g1, 256, 0, stream>>>(mfb, 320, wcat, 320, 320, 0, ml_b, qb, metal2, qk);
        dim3 g2(8, 5);   // M=1024, N=320, K=256
        k_mm<<<g2, 256, 0, stream>>>(qb, 256, wkTb, 256, 256, 1, ml_b, qb, metal2, qk);
    }

    for (int l = 0; l < NLAYERS; ++l) {
        dim3 g(MPAD / 128, 2);
        k_gemm<<<g, 256, 0, stream>>>(h, wb + (size_t)l * 102400, mh);
        k_aggr<<<(NNODES + 3) / 4, 256, 0, stream>>>(mh, pack, offs, prm + (size_t)l * 1520, h,
                                                     (l < NLAYERS - 1) ? 1 : 0);
    }

    k_pool<<<1000, 320, 0, stream>>>(h, qk, wpool, meanp);
    k_head<<<1000, 512, 0, stream>>>(wpool, meanp, metal2, wvT, lgwT, lg_b,
                                     ph1wT, ph1_b, ph2_w, ph2_b, (float*)d_out);
}

// Round 10
// 650.397 us; speedup vs baseline: 1.3645x; 1.3645x over previous
//
#include <hip/hip_runtime.h>
#include <hip/hip_bf16.h>
#include <math.h>

#define NNODES  50000
#define NEDGES  200000
#define NTOT    250000      // E + N self loops
#define EMB     300
#define LDK     320         // padded K stride (bf16 h / mh / weights)
#define MPAD    50048       // 391 * 128 (GEMM M padding)
#define NLAYERS 5
#define NSCAN   49          // ceil(NNODES / 1024)

struct EdgeRec { int r; float c0, c1; };

typedef __attribute__((ext_vector_type(8))) short short8;
typedef __attribute__((ext_vector_type(4))) short short4v;
typedef __attribute__((ext_vector_type(4))) float floatx4;

__device__ inline void gll16(const void* g, void* s) {
    __builtin_amdgcn_global_load_lds((const __attribute__((address_space(1))) unsigned*)g,
                                     (__attribute__((address_space(3))) unsigned*)s, 16, 0, 0);
}

// ---------------- merged transposes for readout weights (head path only) ----------------
__global__ void k_trall(const float* __restrict__ wv, const float* __restrict__ lg_w,
                        const float* __restrict__ ph1_w, const float* __restrict__ me1_w,
                        float* __restrict__ wvT, float* __restrict__ lgwT,
                        float* __restrict__ ph1wT, float* __restrict__ me1wT) {
    int idx = blockIdx.x * 256 + threadIdx.x;
    if (idx < 76800) { int r = idx / 300, c = idx % 300; wvT[c * 256 + r] = wv[idx]; return; }
    idx -= 76800;
    if (idx < 76800) { int r = idx / 300, c = idx % 300; lgwT[c * 256 + r] = lg_w[idx]; return; }
    idx -= 76800;
    if (idx < 131072) { int r = idx / 256, c = idx % 256; ph1wT[c * 512 + r] = ph1_w[idx]; return; }
    idx -= 131072;
    if (idx < 5100) { int r = idx / 17, c = idx % 17; me1wT[c * 300 + r] = me1_w[idx]; }
}

// ---------------- weight convert: wb[l][320][320] = bf16(mlp_w[l][300][300]) zero-padded ----------------
__global__ void k_cvt(const float* __restrict__ w, __hip_bfloat16* __restrict__ wb) {
    int idx = blockIdx.x * 256 + threadIdx.x;
    if (idx >= 5 * 320 * 320) return;
    int l = idx / 102400, r = idx % 102400, n = r / 320, k = r % 320;
    float v = (n < 300 && k < 300) ? w[l * 90000 + n * 300 + k] : 0.f;
    wb[idx] = __float2bfloat16(v);
}

// ---------------- metal-path weight packs: wcat[512][320] = [wq; ml_w], wkTb[320][256] = wk^T ----------------
__global__ void k_cvt2(const float* __restrict__ wq, const float* __restrict__ ml_w,
                       const float* __restrict__ wk,
                       __hip_bfloat16* __restrict__ wcat, __hip_bfloat16* __restrict__ wkTb) {
    int idx = blockIdx.x * 256 + threadIdx.x;
    if (idx < 512 * 320) {
        int r = idx / 320, k = idx % 320;
        float v = 0.f;
        if (k < 300) v = (r < 256) ? wq[r * 300 + k] : ml_w[(r - 256) * 300 + k];
        wcat[idx] = __float2bfloat16(v);
        return;
    }
    idx -= 512 * 320;
    if (idx < 320 * 256) {
        int c = idx / 256, j = idx % 256;
        float v = (c < 300) ? wk[j * 300 + c] : 0.f;
        wkTb[idx] = __float2bfloat16(v);
    }
}

// ---------------- mf = me1b + me2[mt] + mfeat @ me1wT, bf16 [1024,320] (pads pre-zeroed) ----------------
__global__ __launch_bounds__(256) void k_mf(const int* __restrict__ mt, const float* __restrict__ mfeat,
                                            const float* __restrict__ me1wT, const float* __restrict__ me1b,
                                            const float* __restrict__ me2,
                                            __hip_bfloat16* __restrict__ mfb) {
    int idx = blockIdx.x * 256 + threadIdx.x;
    if (idx >= 1000 * 300) return;
    int g = idx / 300, c = idx % 300;
    float v = me1b[c] + me2[(size_t)mt[g] * 300 + c];
    #pragma unroll
    for (int k = 0; k < 17; ++k) v += mfeat[g * 17 + k] * me1wT[k * 300 + c];
    mfb[(size_t)g * 320 + c] = __float2bfloat16(v);
}

// ---------------- generic 128x64 MFMA GEMM for metal path ----------------
__global__ __launch_bounds__(256) void k_mm(const __hip_bfloat16* __restrict__ A, int lda,
                                            const __hip_bfloat16* __restrict__ B, int ldb,
                                            int K, int mode,
                                            const float* __restrict__ mlb,
                                            __hip_bfloat16* __restrict__ qb,
                                            float* __restrict__ metal2,
                                            float* __restrict__ qkout) {
    __shared__ __hip_bfloat16 As[128 * 32];
    __shared__ __hip_bfloat16 Bs[64 * 32];
    int tid = threadIdx.x, lane = tid & 63, w = tid >> 6;
    int row0 = blockIdx.x * 128, col0 = blockIdx.y * 64;

    floatx4 acc[2][4];
    #pragma unroll
    for (int i = 0; i < 2; ++i)
        #pragma unroll
        for (int j = 0; j < 4; ++j) acc[i][j] = (floatx4){0.f, 0.f, 0.f, 0.f};

    const __hip_bfloat16* ga0 = A + (size_t)(row0 + w * 32 + (lane >> 2)) * lda + (lane & 3) * 8;
    const __hip_bfloat16* ga1 = ga0 + (size_t)16 * lda;
    const __hip_bfloat16* gb  = B + (size_t)(col0 + w * 16 + (lane >> 2)) * ldb + (lane & 3) * 8;
    __hip_bfloat16* sa0 = &As[(w * 32) * 32];
    __hip_bfloat16* sa1 = &As[(w * 32 + 16) * 32];
    __hip_bfloat16* sb  = &Bs[(w * 16) * 32];

    int m15 = lane & 15, kof = (lane >> 4) * 8;

    for (int k0 = 0; k0 < K; k0 += 32) {
        __syncthreads();
        gll16(ga0 + k0, sa0);
        gll16(ga1 + k0, sa1);
        gll16(gb  + k0, sb);
        __syncthreads();

        short8 a[2], b[4];
        a[0] = *(const short8*)&As[(w * 32 +      m15) * 32 + kof];
        a[1] = *(const short8*)&As[(w * 32 + 16 + m15) * 32 + kof];
        #pragma unroll
        for (int nt = 0; nt < 4; ++nt)
            b[nt] = *(const short8*)&Bs[(nt * 16 + m15) * 32 + kof];

        #pragma unroll
        for (int mt = 0; mt < 2; ++mt)
            #pragma unroll
            for (int nt = 0; nt < 4; ++nt)
                acc[mt][nt] = __builtin_amdgcn_mfma_f32_16x16x32_bf16(a[mt], b[nt], acc[mt][nt], 0, 0, 0);
    }

    int rbase = row0 + w * 32 + (lane >> 4) * 4;
    #pragma unroll
    for (int mt = 0; mt < 2; ++mt)
        #pragma unroll
        for (int i = 0; i < 4; ++i) {
            int gr = rbase + mt * 16 + i;
            #pragma unroll
            for (int nt = 0; nt < 4; ++nt) {
                int gc = col0 + nt * 16 + m15;
                float v = acc[mt][nt][i];
                if (mode == 0) {
                    if (gc < 256) qb[(size_t)gr * 256 + gc] = __float2bfloat16(v);
                    else if (gr < 1000) metal2[(size_t)gr * 256 + (gc - 256)] = fmaxf(v + mlb[gc - 256], 0.f);
                } else {
                    if (gc < 300 && gr < 1000) qkout[(size_t)gr * 320 + gc] = v;
                }
            }
        }
}

// ---------------- node init: h = bf16(x_emb[x_type] + x_feat @ x_weight), 8 cols/thread ----------------
__global__ __launch_bounds__(256) void k_init(const int* __restrict__ xt,
                                              const float* __restrict__ xf,
                                              const float* __restrict__ xemb,
                                              const float* __restrict__ xw,
                                              __hip_bfloat16* __restrict__ h) {
    int gid = blockIdx.x * 256 + threadIdx.x;
    if (gid >= NNODES * 38) return;
    int n = gid / 38, c = (gid % 38) * 8;     // c in {0,8,...,296}
    bool full = (c <= 292);
    const float* er = xemb + (size_t)xt[n] * 300 + c;
    float v[8];
    float4 e0 = *(const float4*)er;
    v[0] = e0.x; v[1] = e0.y; v[2] = e0.z; v[3] = e0.w;
    if (full) { float4 e1 = *(const float4*)(er + 4); v[4] = e1.x; v[5] = e1.y; v[6] = e1.z; v[7] = e1.w; }
    else      { v[4] = v[5] = v[6] = v[7] = 0.f; }
    float fs[16];
    const float4* xf4 = (const float4*)(xf + n * 16);
    #pragma unroll
    for (int q = 0; q < 4; ++q) {
        float4 t = xf4[q];
        fs[4 * q] = t.x; fs[4 * q + 1] = t.y; fs[4 * q + 2] = t.z; fs[4 * q + 3] = t.w;
    }
    #pragma unroll
    for (int k = 0; k < 16; ++k) {
        const float* wr = xw + k * 300 + c;
        float4 w0 = *(const float4*)wr;
        v[0] += fs[k] * w0.x; v[1] += fs[k] * w0.y; v[2] += fs[k] * w0.z; v[3] += fs[k] * w0.w;
        if (full) {
            float4 w1 = *(const float4*)(wr + 4);
            v[4] += fs[k] * w1.x; v[5] += fs[k] * w1.y; v[6] += fs[k] * w1.z; v[7] += fs[k] * w1.w;
        }
    }
    alignas(16) __hip_bfloat16 ob[8];
    #pragma unroll
    for (int i = 0; i < 8; ++i) ob[i] = __float2bfloat16(v[i]);
    __hip_bfloat16* hp = h + (size_t)n * LDK + c;
    if (full) *(short8*)hp  = *(const short8*)ob;
    else      *(short4v*)hp = *(const short4v*)ob;
}

// ---------------- CSR build ----------------
__global__ void k_count(const int* __restrict__ ei, int* __restrict__ cnt) {
    int e = blockIdx.x * blockDim.x + threadIdx.x;
    if (e >= NTOT) return;
    int c = (e < NEDGES) ? ei[NEDGES + e] : (e - NEDGES);
    atomicAdd(&cnt[c], 1);
}

__global__ __launch_bounds__(1024) void k_scan1(const int* __restrict__ cnt, int* __restrict__ off,
                                                int* __restrict__ bsum) {
    int tid = threadIdx.x;
    int gid = blockIdx.x * 1024 + tid;
    int lane = tid & 63, wv = tid >> 6;
    int v = (gid < NNODES) ? cnt[gid] : 0;
    int x = v;
    #pragma unroll
    for (int s = 1; s < 64; s <<= 1) {
        int t = __shfl_up(x, s, 64);
        if (lane >= s) x += t;
    }
    __shared__ int wsum[16];
    if (lane == 63) wsum[wv] = x;
    __syncthreads();
    if (wv == 0) {
        int w = (lane < 16) ? wsum[lane] : 0;
        #pragma unroll
        for (int s = 1; s < 16; s <<= 1) {
            int t = __shfl_up(w, s, 64);
            if (lane >= s) w += t;
        }
        if (lane < 16) wsum[lane] = w;
    }
    __syncthreads();
    int base = (wv > 0) ? wsum[wv - 1] : 0;
    int incl = x + base;
    if (gid < NNODES) off[gid] = incl - v;
    if (tid == 1023) bsum[blockIdx.x] = incl;
}

__global__ __launch_bounds__(64) void k_scan2(int* __restrict__ bsum) {
    int lane = threadIdx.x;
    int v = (lane < NSCAN) ? bsum[lane] : 0;
    int x = v;
    #pragma unroll
    for (int s = 1; s < 64; s <<= 1) {
        int t = __shfl_up(x, s, 64);
        if (lane >= s) x += t;
    }
    if (lane < NSCAN) bsum[lane] = x - v;
}

__global__ __launch_bounds__(1024) void k_scan3(int* __restrict__ off, const int* __restrict__ bsum) {
    int gid = blockIdx.x * 1024 + threadIdx.x;
    if (gid < NNODES) off[gid] += bsum[blockIdx.x];
    if (gid == 0) off[NNODES] = NTOT;
}

__global__ void k_fill(const int* __restrict__ ei, const float* __restrict__ ea,
                       const int* __restrict__ off, int* __restrict__ cur,
                       EdgeRec* __restrict__ pack) {
    int e = blockIdx.x * blockDim.x + threadIdx.x;
    if (e >= NTOT) return;
    int r, c; float c0, c1;
    if (e < NEDGES) { r = ei[e]; c = ei[NEDGES + e]; c0 = ea[2 * e]; c1 = ea[2 * e + 1]; }
    else            { r = c = e - NEDGES; c0 = 0.f; c1 = 4.f; }
    int p = atomicAdd(&cur[c], 1);
    EdgeRec rec; rec.r = r; rec.c0 = c0; rec.c1 = c1;
    pack[off[c] + p] = rec;
}

// ---------------- per-layer precompute, all layers in one launch ----------------
__global__ __launch_bounds__(64) void k_prep(const float* __restrict__ mlp_w, const float* __restrict__ ew1,
                                             const float* __restrict__ mlp_b, const float* __restrict__ bn_g,
                                             const float* __restrict__ bn_b, const float* __restrict__ bn_rm,
                                             const float* __restrict__ bn_rv, float* __restrict__ prm) {
    int j = blockIdx.x, l = blockIdx.y;
    int lane = threadIdx.x;
    const float* W  = mlp_w + (size_t)l * 90000 + (size_t)j * 300;
    const float* ew = ew1 + l * 600;
    float a0 = 0.f, a1 = 0.f;
    #pragma unroll
    for (int i = 0; i < 5; ++i) {
        int k = lane + i * 64;
        if (k < 300) {
            float w = W[k];
            a0 += w * ew[k];
            a1 += w * ew[300 + k];
        }
    }
    #pragma unroll
    for (int s = 32; s > 0; s >>= 1) { a0 += __shfl_xor(a0, s, 64); a1 += __shfl_xor(a1, s, 64); }
    if (lane == 0) {
        float* p = prm + l * 1520;
        p[j] = a0;
        p[304 + j] = a1;
        p[608 + j] = mlp_b[l * 300 + j];
        float sc = bn_g[l * 300 + j] * rsqrtf(bn_rv[l * 300 + j] + 1e-5f);
        p[912 + j] = sc;
        p[1216 + j] = bn_b[l * 300 + j] - bn_rm[l * 300 + j] * sc;
    }
}

// ---------------- MFMA GEMM (layers): LDS-staged 128x160 block, XCD-swizzled grid ----------------
// 1-D grid of 784 blocks: rowblk=(b>>4)*8+(b&7), col=(b>>3)&1 -> both col-passes of a
// row strip share b%8 (same XCD under round-robin dispatch) so A is L2-resident for pass 2.
__global__ __launch_bounds__(256) void k_gemm(const __hip_bfloat16* __restrict__ A,
                                              const __hip_bfloat16* __restrict__ B,
                                              __hip_bfloat16* __restrict__ C) {
    int b = blockIdx.x;
    int rowblk = (b >> 4) * 8 + (b & 7);
    if (rowblk >= 391) return;
    int row0 = rowblk * 128;
    int col0 = ((b >> 3) & 1) * 160;

    __shared__ __hip_bfloat16 As[128 * 32];
    __shared__ __hip_bfloat16 Bs[160 * 32];
    int tid = threadIdx.x;
    int lane = tid & 63, w = tid >> 6;

    floatx4 acc[2][10];
    #pragma unroll
    for (int i = 0; i < 2; ++i)
        #pragma unroll
        for (int j = 0; j < 10; ++j) acc[i][j] = (floatx4){0.f, 0.f, 0.f, 0.f};

    const __hip_bfloat16* ga0 = A + (size_t)(row0 + w * 32 + (lane >> 2)) * LDK + (lane & 3) * 8;
    const __hip_bfloat16* ga1 = ga0 + (size_t)16 * LDK;
    __hip_bfloat16* sa0 = &As[(w * 32) * 32];
    __hip_bfloat16* sa1 = &As[(w * 32 + 16) * 32];
    int brow0 = (w < 2) ? w * 48 : 96 + (w - 2) * 32;
    int nb = (w < 2) ? 3 : 2;
    const __hip_bfloat16* gb = B + (size_t)(col0 + brow0 + (lane >> 2)) * LDK + (lane & 3) * 8;
    __hip_bfloat16* sb = &Bs[brow0 * 32];

    int m15 = lane & 15, kof = (lane >> 4) * 8;

    for (int k0 = 0; k0 < LDK; k0 += 32) {
        __syncthreads();
        gll16(ga0 + k0, sa0);
        gll16(ga1 + k0, sa1);
        for (int i = 0; i < nb; ++i)
            gll16(gb + (size_t)i * 16 * LDK + k0, sb + i * 16 * 32);
        __syncthreads();

        short8 a[2], bb[10];
        a[0] = *(const short8*)&As[(w * 32 +      m15) * 32 + kof];
        a[1] = *(const short8*)&As[(w * 32 + 16 + m15) * 32 + kof];
        #pragma unroll
        for (int nt = 0; nt < 10; ++nt)
            bb[nt] = *(const short8*)&Bs[(nt * 16 + m15) * 32 + kof];

        #pragma unroll
        for (int mt = 0; mt < 2; ++mt)
            #pragma unroll
            for (int nt = 0; nt < 10; ++nt)
                acc[mt][nt] = __builtin_amdgcn_mfma_f32_16x16x32_bf16(a[mt], bb[nt], acc[mt][nt], 0, 0, 0);
    }

    int rbase = row0 + w * 32 + (lane >> 4) * 4;
    #pragma unroll
    for (int mt = 0; mt < 2; ++mt)
        #pragma unroll
        for (int i = 0; i < 4; ++i) {
            long gr = rbase + mt * 16 + i;
            #pragma unroll
            for (int nt = 0; nt < 10; ++nt)
                C[gr * LDK + col0 + nt * 16 + m15] = __float2bfloat16(acc[mt][nt][i]);
        }
}

// ---------------- aggregate: wave/node, 2-edge unroll (R7 version) ----------------
__global__ __launch_bounds__(256) void k_aggr(const __hip_bfloat16* __restrict__ mh,
                                              const EdgeRec* __restrict__ pack,
                                              const int* __restrict__ off, const float* __restrict__ prm,
                                              __hip_bfloat16* __restrict__ h, int do_relu) {
    int wave = threadIdx.x >> 6;
    int lane = threadIdx.x & 63;
    int n = blockIdx.x * 4 + wave;
    if (n >= NNODES) return;
    float u0[3][2], u1[3][2], bv[3][2], sc[3][2], sh[3][2], acc[3][2];
    #pragma unroll
    for (int i = 0; i < 3; ++i) {
        int j = 2 * lane + 128 * i;
        #pragma unroll
        for (int t = 0; t < 2; ++t) {
            bool ok = (j + t) < 300;
            u0[i][t] = ok ? prm[j + t]        : 0.f;
            u1[i][t] = ok ? prm[304 + j + t]  : 0.f;
            bv[i][t] = ok ? prm[608 + j + t]  : 0.f;
            sc[i][t] = ok ? prm[912 + j + t]  : 0.f;
            sh[i][t] = ok ? prm[1216 + j + t] : 0.f;
            acc[i][t] = 0.f;
        }
    }
    int p0 = off[n], p1 = off[n + 1];
    int p = p0;
    for (; p + 1 < p1; p += 2) {
        EdgeRec e0 = pack[p], e1 = pack[p + 1];
        const __hip_bfloat16* b0 = mh + (size_t)e0.r * LDK;
        const __hip_bfloat16* b1 = mh + (size_t)e1.r * LDK;
        __hip_bfloat162 hv0[3], hv1[3];
        #pragma unroll
        for (int i = 0; i < 3; ++i) {
            int j = 2 * lane + 128 * i;
            if (j < 300) {
                hv0[i] = *(const __hip_bfloat162*)&b0[j];
                hv1[i] = *(const __hip_bfloat162*)&b1[j];
            }
        }
        #pragma unroll
        for (int i = 0; i < 3; ++i) {
            int j = 2 * lane + 128 * i;
            if (j < 300) {
                acc[i][0] += fmaxf(__bfloat162float(hv0[i].x) + e0.c0 * u0[i][0] + e0.c1 * u1[i][0] + bv[i][0], 0.f);
                acc[i][1] += fmaxf(__bfloat162float(hv0[i].y) + e0.c0 * u0[i][1] + e0.c1 * u1[i][1] + bv[i][1], 0.f);
                acc[i][0] += fmaxf(__bfloat162float(hv1[i].x) + e1.c0 * u0[i][0] + e1.c1 * u1[i][0] + bv[i][0], 0.f);
                acc[i][1] += fmaxf(__bfloat162float(hv1[i].y) + e1.c0 * u0[i][1] + e1.c1 * u1[i][1] + bv[i][1], 0.f);
            }
        }
    }
    if (p < p1) {
        EdgeRec e0 = pack[p];
        const __hip_bfloat16* b0 = mh + (size_t)e0.r * LDK;
        #pragma unroll
        for (int i = 0; i < 3; ++i) {
            int j = 2 * lane + 128 * i;
            if (j < 300) {
                __hip_bfloat162 hv = *(const __hip_bfloat162*)&b0[j];
                acc[i][0] += fmaxf(__bfloat162float(hv.x) + e0.c0 * u0[i][0] + e0.c1 * u1[i][0] + bv[i][0], 0.f);
                acc[i][1] += fmaxf(__bfloat162float(hv.y) + e0.c0 * u0[i][1] + e0.c1 * u1[i][1] + bv[i][1], 0.f);
            }
        }
    }
    #pragma unroll
    for (int i = 0; i < 3; ++i) {
        int j = 2 * lane + 128 * i;
        if (j < 300) {
            float v0 = acc[i][0] * sc[i][0] + sh[i][0];
            float v1 = acc[i][1] * sc[i][1] + sh[i][1];
            if (do_relu) { v0 = fmaxf(v0, 0.f); v1 = fmaxf(v1, 0.f); }
            __hip_bfloat162 o;
            o.x = __float2bfloat16(v0);
            o.y = __float2bfloat16(v1);
            *(__hip_bfloat162*)&h[(size_t)n * LDK + j] = o;
        }
    }
}

// ---------------- attention pool (LDS-cached h tile, read h once) ----------------
__global__ __launch_bounds__(320) void k_pool(const __hip_bfloat16* __restrict__ h, const float* __restrict__ qk,
                                              float* __restrict__ wpool, float* __restrict__ mean) {
    int b = blockIdx.x;
    int tid = threadIdx.x;
    int wave = tid >> 6, lane = tid & 63;
    __shared__ float qk_s[300];
    __shared__ float sc[50];
    __shared__ __hip_bfloat16 hs[50][304];
    if (tid < 300) qk_s[tid] = qk[(size_t)b * 320 + tid];
    __syncthreads();
    for (int k = wave; k < 50; k += 5) {
        const __hip_bfloat16* hp = h + (long)(b * 50 + k) * LDK;
        float partial = 0.f;
        #pragma unroll
        for (int i = 0; i < 5; ++i) {
            int j = lane + i * 64;
            if (j < 300) {
                __hip_bfloat16 hv = hp[j];
                hs[k][j] = hv;
                partial += __bfloat162float(hv) * qk_s[j];
            }
        }
        #pragma unroll
        for (int s = 32; s > 0; s >>= 1) partial += __shfl_xor(partial, s, 64);
        if (lane == 0) sc[k] = partial * (1.f / 16.f);
    }
    __syncthreads();
    if (tid == 0) {
        float mx = sc[0];
        for (int k = 1; k < 50; ++k) mx = fmaxf(mx, sc[k]);
        float s = 0.f;
        for (int k = 0; k < 50; ++k) { float e = __expf(sc[k] - mx); sc[k] = e; s += e; }
        float inv = 1.f / s;
        for (int k = 0; k < 50; ++k) sc[k] *= inv;
    }
    __syncthreads();
    if (tid < 300) {
        float aw = 0.f, am = 0.f;
        for (int k = 0; k < 50; ++k) {
            float v = __bfloat162float(hs[k][tid]);
            aw += sc[k] * v;
            am += v;
        }
        wpool[b * 300 + tid] = aw;
        mean[b * 300 + tid]  = am * (1.f / 50.f);
    }
}

// ---------------- head (coalesced via transposed weights) ----------------
__global__ __launch_bounds__(512) void k_head(const float* __restrict__ wpool, const float* __restrict__ mean,
                                              const float* __restrict__ metal2,
                                              const float* __restrict__ wvT, const float* __restrict__ lgwT,
                                              const float* __restrict__ lgb,
                                              const float* __restrict__ ph1wT, const float* __restrict__ ph1b,
                                              const float* __restrict__ ph2w, const float* __restrict__ ph2b,
                                              float* __restrict__ out) {
    int b = blockIdx.x;
    int tid = threadIdx.x;
    __shared__ float wp_s[300], mn_s[300], f_s[256], red[512];
    if (tid < 300) { wp_s[tid] = wpool[b * 300 + tid]; mn_s[tid] = mean[b * 300 + tid]; }
    __syncthreads();
    if (tid < 256) {
        float att = 0.f, lg = 0.f;
        #pragma unroll 4
        for (int k = 0; k < 300; ++k) {
            att += wp_s[k] * wvT[k * 256 + tid];
            lg  += mn_s[k] * lgwT[k * 256 + tid];
        }
        lg = fmaxf(lg + lgb[tid], 0.f);
        f_s[tid] = fmaxf(att, 0.f) + metal2[b * 256 + tid] + lg;
    }
    __syncthreads();
    float a = ph1b[tid];
    #pragma unroll 8
    for (int k = 0; k < 256; ++k) a += f_s[k] * ph1wT[k * 512 + tid];
    float sp = fmaxf(a, 0.f) + log1pf(__expf(-fabsf(a)));   // stable softplus
    red[tid] = sp * ph2w[tid];
    __syncthreads();
    for (int s = 256; s > 0; s >>= 1) {
        if (tid < s) red[tid] += red[tid + s];
        __syncthreads();
    }
    if (tid == 0) out[b] = red[0] + ph2b[0];
}

extern "C" void kernel_launch(void* const* d_in, const int* in_sizes, int n_in,
                              void* d_out, int out_size, void* d_ws, size_t ws_size,
                              hipStream_t stream) {
    const int*   x_type   = (const int*)d_in[0];
    const float* x_feat   = (const float*)d_in[1];
    const int*   eindex   = (const int*)d_in[2];
    const float* eattr    = (const float*)d_in[3];
    const int*   mtype    = (const int*)d_in[4];
    const float* mfeat    = (const float*)d_in[5];
    const float* x_emb    = (const float*)d_in[6];
    const float* x_weight = (const float*)d_in[7];
    const float* ew1      = (const float*)d_in[8];
    const float* mlp_w    = (const float*)d_in[9];
    const float* mlp_b    = (const float*)d_in[10];
    const float* bn_g     = (const float*)d_in[11];
    const float* bn_b     = (const float*)d_in[12];
    const float* bn_rm    = (const float*)d_in[13];
    const float* bn_rv    = (const float*)d_in[14];
    const float* me1_w    = (const float*)d_in[15];
    const float* me1_b    = (const float*)d_in[16];
    const float* me2      = (const float*)d_in[17];
    const float* wq       = (const float*)d_in[18];
    const float* wk       = (const float*)d_in[19];
    const float* wv       = (const float*)d_in[20];
    const float* ml_w     = (const float*)d_in[21];
    const float* ml_b     = (const float*)d_in[22];
    const float* lg_w     = (const float*)d_in[23];
    const float* lg_b     = (const float*)d_in[24];
    const float* ph1_w    = (const float*)d_in[25];
    const float* ph1_b    = (const float*)d_in[26];
    const float* ph2_w    = (const float*)d_in[27];
    const float* ph2_b    = (const float*)d_in[28];

    char* ws = (char*)d_ws;
    size_t o = 0;
    auto alloc = [&](size_t bytes) -> void* {
        void* p = ws + o;
        o += (bytes + 255) & ~(size_t)255;
        return p;
    };
    __hip_bfloat16* h    = (__hip_bfloat16*)alloc((size_t)MPAD * LDK * 2);
    __hip_bfloat16* mh   = (__hip_bfloat16*)alloc((size_t)MPAD * LDK * 2);
    __hip_bfloat16* wb   = (__hip_bfloat16*)alloc((size_t)5 * 320 * 320 * 2);
    int*     cnt    = (int*)alloc((size_t)NNODES * 4);
    int*     offs   = (int*)alloc((size_t)(NNODES + 1) * 4);
    int*     cur    = (int*)alloc((size_t)NNODES * 4);
    int*     bsum   = (int*)alloc((size_t)64 * 4);
    EdgeRec* pack   = (EdgeRec*)alloc((size_t)NTOT * sizeof(EdgeRec));
    float*   prm    = (float*)alloc((size_t)NLAYERS * 1520 * 4);
    float*   metal2 = (float*)alloc((size_t)1000 * 256 * 4);
    float*   qk     = (float*)alloc((size_t)1024 * 320 * 4);
    float*   wpool  = (float*)alloc((size_t)1000 * 300 * 4);
    float*   meanp  = (float*)alloc((size_t)1000 * 300 * 4);
    float*   wvT    = (float*)alloc((size_t)300 * 256 * 4);
    float*   lgwT   = (float*)alloc((size_t)300 * 256 * 4);
    float*   ph1wT  = (float*)alloc((size_t)256 * 512 * 4);
    float*   me1wT  = (float*)alloc((size_t)17 * 300 * 4);
    __hip_bfloat16* mfb  = (__hip_bfloat16*)alloc((size_t)1024 * 320 * 2);
    __hip_bfloat16* wcat = (__hip_bfloat16*)alloc((size_t)512 * 320 * 2);
    __hip_bfloat16* wkTb = (__hip_bfloat16*)alloc((size_t)320 * 256 * 2);
    __hip_bfloat16* qb   = (__hip_bfloat16*)alloc((size_t)1024 * 256 * 2);
    (void)ws_size; (void)in_sizes; (void)n_in; (void)out_size;

    hipMemsetAsync(cnt, 0, (size_t)NNODES * 4, stream);
    hipMemsetAsync(cur, 0, (size_t)NNODES * 4, stream);
    hipMemsetAsync(mfb, 0, (size_t)1024 * 320 * 2, stream);

    k_cvt<<<(5 * 320 * 320 + 255) / 256, 256, 0, stream>>>(mlp_w, wb);
    k_cvt2<<<(512 * 320 + 320 * 256 + 255) / 256, 256, 0, stream>>>(wq, ml_w, wk, wcat, wkTb);
    k_trall<<<(289772 + 255) / 256, 256, 0, stream>>>(wv, lg_w, ph1_w, me1_w, wvT, lgwT, ph1wT, me1wT);
    k_init<<<(NNODES * 38 + 255) / 256, 256, 0, stream>>>(x_type, x_feat, x_emb, x_weight, h);
    k_count<<<(NTOT + 255) / 256, 256, 0, stream>>>(eindex, cnt);
    k_scan1<<<NSCAN, 1024, 0, stream>>>(cnt, offs, bsum);
    k_scan2<<<1, 64, 0, stream>>>(bsum);
    k_scan3<<<NSCAN, 1024, 0, stream>>>(offs, bsum);
    k_fill<<<(NTOT + 255) / 256, 256, 0, stream>>>(eindex, eattr, offs, cur, pack);
    {
        dim3 gp(300, NLAYERS);
        k_prep<<<gp, 64, 0, stream>>>(mlp_w, ew1, mlp_b, bn_g, bn_b, bn_rm, bn_rv, prm);
    }
    // metal path: mf -> {q, metal2} -> qk  (batched MFMA GEMMs)
    k_mf<<<(1000 * 300 + 255) / 256, 256, 0, stream>>>(mtype, mfeat, me1wT, me1_b, me2, mfb);
    {
        dim3 g1(8, 8);   // M=1024, N=512, K=320
        k_mm<<<g1, 256, 0, stream>>>(mfb, 320, wcat, 320, 320, 0, ml_b, qb, metal2, qk);
        dim3 g2(8, 5);   // M=1024, N=320, K=256
        k_mm<<<g2, 256, 0, stream>>>(qb, 256, wkTb, 256, 256, 1, ml_b, qb, metal2, qk);
    }

    for (int l = 0; l < NLAYERS; ++l) {
        k_gemm<<<784, 256, 0, stream>>>(h, wb + (size_t)l * 102400, mh);
        k_aggr<<<(NNODES + 3) / 4, 256, 0, stream>>>(mh, pack, offs, prm + (size_t)l * 1520, h,
                                                     (l < NLAYERS - 1) ? 1 : 0);
    }

    k_pool<<<1000, 320, 0, stream>>>(h, qk, wpool, meanp);
    k_head<<<1000, 512, 0, stream>>>(wpool, meanp, metal2, wvT, lgwT, lg_b,
                                     ph1wT, ph1_b, ph2_w, ph2_b, (float*)d_out);
}

// Round 11
// 612.367 us; speedup vs baseline: 1.4492x; 1.0621x over previous
//
#include <hip/hip_runtime.h>
#include <hip/hip_bf16.h>
#include <math.h>

#define NNODES  50000
#define NEDGES  200000
#define NTOT    250000      // E + N self loops
#define EMB     300
#define LDK     320         // padded K stride (bf16 h / mh / weights)
#define MPAD    50048       // 391 * 128 (GEMM M padding)
#define NLAYERS 5
#define NSCAN   49          // ceil(NNODES / 1024)
#define NPW     4           // nodes per wave in k_aggr (amortize prm prologue)

struct EdgeRec { int r; float c0, c1; };

typedef __attribute__((ext_vector_type(8))) short short8;
typedef __attribute__((ext_vector_type(4))) short short4v;
typedef __attribute__((ext_vector_type(4))) float floatx4;

__device__ inline void gll16(const void* g, void* s) {
    __builtin_amdgcn_global_load_lds((const __attribute__((address_space(1))) unsigned*)g,
                                     (__attribute__((address_space(3))) unsigned*)s, 16, 0, 0);
}

// ---------------- merged transposes for readout weights (head path only) ----------------
__global__ void k_trall(const float* __restrict__ wv, const float* __restrict__ lg_w,
                        const float* __restrict__ ph1_w, const float* __restrict__ me1_w,
                        float* __restrict__ wvT, float* __restrict__ lgwT,
                        float* __restrict__ ph1wT, float* __restrict__ me1wT) {
    int idx = blockIdx.x * 256 + threadIdx.x;
    if (idx < 76800) { int r = idx / 300, c = idx % 300; wvT[c * 256 + r] = wv[idx]; return; }
    idx -= 76800;
    if (idx < 76800) { int r = idx / 300, c = idx % 300; lgwT[c * 256 + r] = lg_w[idx]; return; }
    idx -= 76800;
    if (idx < 131072) { int r = idx / 256, c = idx % 256; ph1wT[c * 512 + r] = ph1_w[idx]; return; }
    idx -= 131072;
    if (idx < 5100) { int r = idx / 17, c = idx % 17; me1wT[c * 300 + r] = me1_w[idx]; }
}

// ---------------- weight convert: wb[l][320][320] = bf16(mlp_w[l][300][300]) zero-padded ----------------
__global__ void k_cvt(const float* __restrict__ w, __hip_bfloat16* __restrict__ wb) {
    int idx = blockIdx.x * 256 + threadIdx.x;
    if (idx >= 5 * 320 * 320) return;
    int l = idx / 102400, r = idx % 102400, n = r / 320, k = r % 320;
    float v = (n < 300 && k < 300) ? w[l * 90000 + n * 300 + k] : 0.f;
    wb[idx] = __float2bfloat16(v);
}

// ---------------- metal-path weight packs: wcat[512][320] = [wq; ml_w], wkTb[320][256] = wk^T ----------------
__global__ void k_cvt2(const float* __restrict__ wq, const float* __restrict__ ml_w,
                       const float* __restrict__ wk,
                       __hip_bfloat16* __restrict__ wcat, __hip_bfloat16* __restrict__ wkTb) {
    int idx = blockIdx.x * 256 + threadIdx.x;
    if (idx < 512 * 320) {
        int r = idx / 320, k = idx % 320;
        float v = 0.f;
        if (k < 300) v = (r < 256) ? wq[r * 300 + k] : ml_w[(r - 256) * 300 + k];
        wcat[idx] = __float2bfloat16(v);
        return;
    }
    idx -= 512 * 320;
    if (idx < 320 * 256) {
        int c = idx / 256, j = idx % 256;
        float v = (c < 300) ? wk[j * 300 + c] : 0.f;
        wkTb[idx] = __float2bfloat16(v);
    }
}

// ---------------- mf = me1b + me2[mt] + mfeat @ me1wT, bf16 [1024,320] (pads pre-zeroed) ----------------
__global__ __launch_bounds__(256) void k_mf(const int* __restrict__ mt, const float* __restrict__ mfeat,
                                            const float* __restrict__ me1wT, const float* __restrict__ me1b,
                                            const float* __restrict__ me2,
                                            __hip_bfloat16* __restrict__ mfb) {
    int idx = blockIdx.x * 256 + threadIdx.x;
    if (idx >= 1000 * 300) return;
    int g = idx / 300, c = idx % 300;
    float v = me1b[c] + me2[(size_t)mt[g] * 300 + c];
    #pragma unroll
    for (int k = 0; k < 17; ++k) v += mfeat[g * 17 + k] * me1wT[k * 300 + c];
    mfb[(size_t)g * 320 + c] = __float2bfloat16(v);
}

// ---------------- generic 128x64 MFMA GEMM for metal path ----------------
__global__ __launch_bounds__(256) void k_mm(const __hip_bfloat16* __restrict__ A, int lda,
                                            const __hip_bfloat16* __restrict__ B, int ldb,
                                            int K, int mode,
                                            const float* __restrict__ mlb,
                                            __hip_bfloat16* __restrict__ qb,
                                            float* __restrict__ metal2,
                                            float* __restrict__ qkout) {
    __shared__ __hip_bfloat16 As[128 * 32];
    __shared__ __hip_bfloat16 Bs[64 * 32];
    int tid = threadIdx.x, lane = tid & 63, w = tid >> 6;
    int row0 = blockIdx.x * 128, col0 = blockIdx.y * 64;

    floatx4 acc[2][4];
    #pragma unroll
    for (int i = 0; i < 2; ++i)
        #pragma unroll
        for (int j = 0; j < 4; ++j) acc[i][j] = (floatx4){0.f, 0.f, 0.f, 0.f};

    const __hip_bfloat16* ga0 = A + (size_t)(row0 + w * 32 + (lane >> 2)) * lda + (lane & 3) * 8;
    const __hip_bfloat16* ga1 = ga0 + (size_t)16 * lda;
    const __hip_bfloat16* gb  = B + (size_t)(col0 + w * 16 + (lane >> 2)) * ldb + (lane & 3) * 8;
    __hip_bfloat16* sa0 = &As[(w * 32) * 32];
    __hip_bfloat16* sa1 = &As[(w * 32 + 16) * 32];
    __hip_bfloat16* sb  = &Bs[(w * 16) * 32];

    int m15 = lane & 15, kof = (lane >> 4) * 8;

    for (int k0 = 0; k0 < K; k0 += 32) {
        __syncthreads();
        gll16(ga0 + k0, sa0);
        gll16(ga1 + k0, sa1);
        gll16(gb  + k0, sb);
        __syncthreads();

        short8 a[2], b[4];
        a[0] = *(const short8*)&As[(w * 32 +      m15) * 32 + kof];
        a[1] = *(const short8*)&As[(w * 32 + 16 + m15) * 32 + kof];
        #pragma unroll
        for (int nt = 0; nt < 4; ++nt)
            b[nt] = *(const short8*)&Bs[(nt * 16 + m15) * 32 + kof];

        #pragma unroll
        for (int mt = 0; mt < 2; ++mt)
            #pragma unroll
            for (int nt = 0; nt < 4; ++nt)
                acc[mt][nt] = __builtin_amdgcn_mfma_f32_16x16x32_bf16(a[mt], b[nt], acc[mt][nt], 0, 0, 0);
    }

    int rbase = row0 + w * 32 + (lane >> 4) * 4;
    #pragma unroll
    for (int mt = 0; mt < 2; ++mt)
        #pragma unroll
        for (int i = 0; i < 4; ++i) {
            int gr = rbase + mt * 16 + i;
            #pragma unroll
            for (int nt = 0; nt < 4; ++nt) {
                int gc = col0 + nt * 16 + m15;
                float v = acc[mt][nt][i];
                if (mode == 0) {
                    if (gc < 256) qb[(size_t)gr * 256 + gc] = __float2bfloat16(v);
                    else if (gr < 1000) metal2[(size_t)gr * 256 + (gc - 256)] = fmaxf(v + mlb[gc - 256], 0.f);
                } else {
                    if (gc < 300 && gr < 1000) qkout[(size_t)gr * 320 + gc] = v;
                }
            }
        }
}

// ---------------- node init: h = bf16(x_emb[x_type] + x_feat @ x_weight), 8 cols/thread ----------------
__global__ __launch_bounds__(256) void k_init(const int* __restrict__ xt,
                                              const float* __restrict__ xf,
                                              const float* __restrict__ xemb,
                                              const float* __restrict__ xw,
                                              __hip_bfloat16* __restrict__ h) {
    int gid = blockIdx.x * 256 + threadIdx.x;
    if (gid >= NNODES * 38) return;
    int n = gid / 38, c = (gid % 38) * 8;     // c in {0,8,...,296}
    bool full = (c <= 292);
    const float* er = xemb + (size_t)xt[n] * 300 + c;
    float v[8];
    float4 e0 = *(const float4*)er;
    v[0] = e0.x; v[1] = e0.y; v[2] = e0.z; v[3] = e0.w;
    if (full) { float4 e1 = *(const float4*)(er + 4); v[4] = e1.x; v[5] = e1.y; v[6] = e1.z; v[7] = e1.w; }
    else      { v[4] = v[5] = v[6] = v[7] = 0.f; }
    float fs[16];
    const float4* xf4 = (const float4*)(xf + n * 16);
    #pragma unroll
    for (int q = 0; q < 4; ++q) {
        float4 t = xf4[q];
        fs[4 * q] = t.x; fs[4 * q + 1] = t.y; fs[4 * q + 2] = t.z; fs[4 * q + 3] = t.w;
    }
    #pragma unroll
    for (int k = 0; k < 16; ++k) {
        const float* wr = xw + k * 300 + c;
        float4 w0 = *(const float4*)wr;
        v[0] += fs[k] * w0.x; v[1] += fs[k] * w0.y; v[2] += fs[k] * w0.z; v[3] += fs[k] * w0.w;
        if (full) {
            float4 w1 = *(const float4*)(wr + 4);
            v[4] += fs[k] * w1.x; v[5] += fs[k] * w1.y; v[6] += fs[k] * w1.z; v[7] += fs[k] * w1.w;
        }
    }
    alignas(16) __hip_bfloat16 ob[8];
    #pragma unroll
    for (int i = 0; i < 8; ++i) ob[i] = __float2bfloat16(v[i]);
    __hip_bfloat16* hp = h + (size_t)n * LDK + c;
    if (full) *(short8*)hp  = *(const short8*)ob;
    else      *(short4v*)hp = *(const short4v*)ob;
}

// ---------------- CSR build ----------------
__global__ void k_count(const int* __restrict__ ei, int* __restrict__ cnt) {
    int e = blockIdx.x * blockDim.x + threadIdx.x;
    if (e >= NTOT) return;
    int c = (e < NEDGES) ? ei[NEDGES + e] : (e - NEDGES);
    atomicAdd(&cnt[c], 1);
}

__global__ __launch_bounds__(1024) void k_scan1(const int* __restrict__ cnt, int* __restrict__ off,
                                                int* __restrict__ bsum) {
    int tid = threadIdx.x;
    int gid = blockIdx.x * 1024 + tid;
    int lane = tid & 63, wv = tid >> 6;
    int v = (gid < NNODES) ? cnt[gid] : 0;
    int x = v;
    #pragma unroll
    for (int s = 1; s < 64; s <<= 1) {
        int t = __shfl_up(x, s, 64);
        if (lane >= s) x += t;
    }
    __shared__ int wsum[16];
    if (lane == 63) wsum[wv] = x;
    __syncthreads();
    if (wv == 0) {
        int w = (lane < 16) ? wsum[lane] : 0;
        #pragma unroll
        for (int s = 1; s < 16; s <<= 1) {
            int t = __shfl_up(w, s, 64);
            if (lane >= s) w += t;
        }
        if (lane < 16) wsum[lane] = w;
    }
    __syncthreads();
    int base = (wv > 0) ? wsum[wv - 1] : 0;
    int incl = x + base;
    if (gid < NNODES) off[gid] = incl - v;
    if (tid == 1023) bsum[blockIdx.x] = incl;
}

__global__ __launch_bounds__(64) void k_scan2(int* __restrict__ bsum) {
    int lane = threadIdx.x;
    int v = (lane < NSCAN) ? bsum[lane] : 0;
    int x = v;
    #pragma unroll
    for (int s = 1; s < 64; s <<= 1) {
        int t = __shfl_up(x, s, 64);
        if (lane >= s) x += t;
    }
    if (lane < NSCAN) bsum[lane] = x - v;
}

__global__ __launch_bounds__(1024) void k_scan3(int* __restrict__ off, const int* __restrict__ bsum) {
    int gid = blockIdx.x * 1024 + threadIdx.x;
    if (gid < NNODES) off[gid] += bsum[blockIdx.x];
    if (gid == 0) off[NNODES] = NTOT;
}

__global__ void k_fill(const int* __restrict__ ei, const float* __restrict__ ea,
                       const int* __restrict__ off, int* __restrict__ cur,
                       EdgeRec* __restrict__ pack) {
    int e = blockIdx.x * blockDim.x + threadIdx.x;
    if (e >= NTOT) return;
    int r, c; float c0, c1;
    if (e < NEDGES) { r = ei[e]; c = ei[NEDGES + e]; c0 = ea[2 * e]; c1 = ea[2 * e + 1]; }
    else            { r = c = e - NEDGES; c0 = 0.f; c1 = 4.f; }
    int p = atomicAdd(&cur[c], 1);
    EdgeRec rec; rec.r = r; rec.c0 = c0; rec.c1 = c1;
    pack[off[c] + p] = rec;
}

// ---------------- per-layer precompute, all layers in one launch ----------------
__global__ __launch_bounds__(64) void k_prep(const float* __restrict__ mlp_w, const float* __restrict__ ew1,
                                             const float* __restrict__ mlp_b, const float* __restrict__ bn_g,
                                             const float* __restrict__ bn_b, const float* __restrict__ bn_rm,
                                             const float* __restrict__ bn_rv, float* __restrict__ prm) {
    int j = blockIdx.x, l = blockIdx.y;
    int lane = threadIdx.x;
    const float* W  = mlp_w + (size_t)l * 90000 + (size_t)j * 300;
    const float* ew = ew1 + l * 600;
    float a0 = 0.f, a1 = 0.f;
    #pragma unroll
    for (int i = 0; i < 5; ++i) {
        int k = lane + i * 64;
        if (k < 300) {
            float w = W[k];
            a0 += w * ew[k];
            a1 += w * ew[300 + k];
        }
    }
    #pragma unroll
    for (int s = 32; s > 0; s >>= 1) { a0 += __shfl_xor(a0, s, 64); a1 += __shfl_xor(a1, s, 64); }
    if (lane == 0) {
        float* p = prm + l * 1520;
        p[j] = a0;
        p[304 + j] = a1;
        p[608 + j] = mlp_b[l * 300 + j];
        float sc = bn_g[l * 300 + j] * rsqrtf(bn_rv[l * 300 + j] + 1e-5f);
        p[912 + j] = sc;
        p[1216 + j] = bn_b[l * 300 + j] - bn_rm[l * 300 + j] * sc;
    }
}

// ---------------- MFMA GEMM (layers): LDS-staged 128x160 block, XCD-swizzled grid ----------------
__global__ __launch_bounds__(256) void k_gemm(const __hip_bfloat16* __restrict__ A,
                                              const __hip_bfloat16* __restrict__ B,
                                              __hip_bfloat16* __restrict__ C) {
    int b = blockIdx.x;
    int rowblk = (b >> 4) * 8 + (b & 7);
    if (rowblk >= 391) return;
    int row0 = rowblk * 128;
    int col0 = ((b >> 3) & 1) * 160;

    __shared__ __hip_bfloat16 As[128 * 32];
    __shared__ __hip_bfloat16 Bs[160 * 32];
    int tid = threadIdx.x;
    int lane = tid & 63, w = tid >> 6;

    floatx4 acc[2][10];
    #pragma unroll
    for (int i = 0; i < 2; ++i)
        #pragma unroll
        for (int j = 0; j < 10; ++j) acc[i][j] = (floatx4){0.f, 0.f, 0.f, 0.f};

    const __hip_bfloat16* ga0 = A + (size_t)(row0 + w * 32 + (lane >> 2)) * LDK + (lane & 3) * 8;
    const __hip_bfloat16* ga1 = ga0 + (size_t)16 * LDK;
    __hip_bfloat16* sa0 = &As[(w * 32) * 32];
    __hip_bfloat16* sa1 = &As[(w * 32 + 16) * 32];
    int brow0 = (w < 2) ? w * 48 : 96 + (w - 2) * 32;
    int nb = (w < 2) ? 3 : 2;
    const __hip_bfloat16* gb = B + (size_t)(col0 + brow0 + (lane >> 2)) * LDK + (lane & 3) * 8;
    __hip_bfloat16* sb = &Bs[brow0 * 32];

    int m15 = lane & 15, kof = (lane >> 4) * 8;

    for (int k0 = 0; k0 < LDK; k0 += 32) {
        __syncthreads();
        gll16(ga0 + k0, sa0);
        gll16(ga1 + k0, sa1);
        for (int i = 0; i < nb; ++i)
            gll16(gb + (size_t)i * 16 * LDK + k0, sb + i * 16 * 32);
        __syncthreads();

        short8 a[2], bb[10];
        a[0] = *(const short8*)&As[(w * 32 +      m15) * 32 + kof];
        a[1] = *(const short8*)&As[(w * 32 + 16 + m15) * 32 + kof];
        #pragma unroll
        for (int nt = 0; nt < 10; ++nt)
            bb[nt] = *(const short8*)&Bs[(nt * 16 + m15) * 32 + kof];

        #pragma unroll
        for (int mt = 0; mt < 2; ++mt)
            #pragma unroll
            for (int nt = 0; nt < 10; ++nt)
                acc[mt][nt] = __builtin_amdgcn_mfma_f32_16x16x32_bf16(a[mt], bb[nt], acc[mt][nt], 0, 0, 0);
    }

    int rbase = row0 + w * 32 + (lane >> 4) * 4;
    #pragma unroll
    for (int mt = 0; mt < 2; ++mt)
        #pragma unroll
        for (int i = 0; i < 4; ++i) {
            long gr = rbase + mt * 16 + i;
            #pragma unroll
            for (int nt = 0; nt < 10; ++nt)
                C[gr * LDK + col0 + nt * 16 + m15] = __float2bfloat16(acc[mt][nt][i]);
        }
}

// ---------------- aggregate: wave handles NPW sequential nodes (prm prologue amortized) ----------------
__global__ __launch_bounds__(256) void k_aggr(const __hip_bfloat16* __restrict__ mh,
                                              const EdgeRec* __restrict__ pack,
                                              const int* __restrict__ off, const float* __restrict__ prm,
                                              __hip_bfloat16* __restrict__ h, int do_relu) {
    int wave = threadIdx.x >> 6;
    int lane = threadIdx.x & 63;
    int n0 = (blockIdx.x * 4 + wave) * NPW;
    if (n0 >= NNODES) return;

    // per-layer constants: loaded ONCE per wave, reused across NPW nodes
    float u0[3][2], u1[3][2], bv[3][2], sc[3][2], sh[3][2];
    #pragma unroll
    for (int i = 0; i < 3; ++i) {
        int j = 2 * lane + 128 * i;
        #pragma unroll
        for (int t = 0; t < 2; ++t) {
            bool ok = (j + t) < 300;
            u0[i][t] = ok ? prm[j + t]        : 0.f;
            u1[i][t] = ok ? prm[304 + j + t]  : 0.f;
            bv[i][t] = ok ? prm[608 + j + t]  : 0.f;
            sc[i][t] = ok ? prm[912 + j + t]  : 0.f;
            sh[i][t] = ok ? prm[1216 + j + t] : 0.f;
        }
    }

    int nend = (n0 + NPW < NNODES) ? n0 + NPW : NNODES;
    for (int n = n0; n < nend; ++n) {
        float acc[3][2];
        #pragma unroll
        for (int i = 0; i < 3; ++i) { acc[i][0] = 0.f; acc[i][1] = 0.f; }
        int p0 = off[n], p1 = off[n + 1];
        int p = p0;
        for (; p + 1 < p1; p += 2) {
            EdgeRec e0 = pack[p], e1 = pack[p + 1];
            const __hip_bfloat16* b0 = mh + (size_t)e0.r * LDK;
            const __hip_bfloat16* b1 = mh + (size_t)e1.r * LDK;
            __hip_bfloat162 hv0[3], hv1[3];
            #pragma unroll
            for (int i = 0; i < 3; ++i) {
                int j = 2 * lane + 128 * i;
                if (j < 300) {
                    hv0[i] = *(const __hip_bfloat162*)&b0[j];
                    hv1[i] = *(const __hip_bfloat162*)&b1[j];
                }
            }
            #pragma unroll
            for (int i = 0; i < 3; ++i) {
                int j = 2 * lane + 128 * i;
                if (j < 300) {
                    acc[i][0] += fmaxf(__bfloat162float(hv0[i].x) + e0.c0 * u0[i][0] + e0.c1 * u1[i][0] + bv[i][0], 0.f);
                    acc[i][1] += fmaxf(__bfloat162float(hv0[i].y) + e0.c0 * u0[i][1] + e0.c1 * u1[i][1] + bv[i][1], 0.f);
                    acc[i][0] += fmaxf(__bfloat162float(hv1[i].x) + e1.c0 * u0[i][0] + e1.c1 * u1[i][0] + bv[i][0], 0.f);
                    acc[i][1] += fmaxf(__bfloat162float(hv1[i].y) + e1.c0 * u0[i][1] + e1.c1 * u1[i][1] + bv[i][1], 0.f);
                }
            }
        }
        if (p < p1) {
            EdgeRec e0 = pack[p];
            const __hip_bfloat16* b0 = mh + (size_t)e0.r * LDK;
            #pragma unroll
            for (int i = 0; i < 3; ++i) {
                int j = 2 * lane + 128 * i;
                if (j < 300) {
                    __hip_bfloat162 hv = *(const __hip_bfloat162*)&b0[j];
                    acc[i][0] += fmaxf(__bfloat162float(hv.x) + e0.c0 * u0[i][0] + e0.c1 * u1[i][0] + bv[i][0], 0.f);
                    acc[i][1] += fmaxf(__bfloat162float(hv.y) + e0.c0 * u0[i][1] + e0.c1 * u1[i][1] + bv[i][1], 0.f);
                }
            }
        }
        #pragma unroll
        for (int i = 0; i < 3; ++i) {
            int j = 2 * lane + 128 * i;
            if (j < 300) {
                float v0 = acc[i][0] * sc[i][0] + sh[i][0];
                float v1 = acc[i][1] * sc[i][1] + sh[i][1];
                if (do_relu) { v0 = fmaxf(v0, 0.f); v1 = fmaxf(v1, 0.f); }
                __hip_bfloat162 o;
                o.x = __float2bfloat16(v0);
                o.y = __float2bfloat16(v1);
                *(__hip_bfloat162*)&h[(size_t)n * LDK + j] = o;
            }
        }
    }
}

// ---------------- attention pool (LDS-cached h tile, read h once) ----------------
__global__ __launch_bounds__(320) void k_pool(const __hip_bfloat16* __restrict__ h, const float* __restrict__ qk,
                                              float* __restrict__ wpool, float* __restrict__ mean) {
    int b = blockIdx.x;
    int tid = threadIdx.x;
    int wave = tid >> 6, lane = tid & 63;
    __shared__ float qk_s[300];
    __shared__ float sc[50];
    __shared__ __hip_bfloat16 hs[50][304];
    if (tid < 300) qk_s[tid] = qk[(size_t)b * 320 + tid];
    __syncthreads();
    for (int k = wave; k < 50; k += 5) {
        const __hip_bfloat16* hp = h + (long)(b * 50 + k) * LDK;
        float partial = 0.f;
        #pragma unroll
        for (int i = 0; i < 5; ++i) {
            int j = lane + i * 64;
            if (j < 300) {
                __hip_bfloat16 hv = hp[j];
                hs[k][j] = hv;
                partial += __bfloat162float(hv) * qk_s[j];
            }
        }
        #pragma unroll
        for (int s = 32; s > 0; s >>= 1) partial += __shfl_xor(partial, s, 64);
        if (lane == 0) sc[k] = partial * (1.f / 16.f);
    }
    __syncthreads();
    if (tid == 0) {
        float mx = sc[0];
        for (int k = 1; k < 50; ++k) mx = fmaxf(mx, sc[k]);
        float s = 0.f;
        for (int k = 0; k < 50; ++k) { float e = __expf(sc[k] - mx); sc[k] = e; s += e; }
        float inv = 1.f / s;
        for (int k = 0; k < 50; ++k) sc[k] *= inv;
    }
    __syncthreads();
    if (tid < 300) {
        float aw = 0.f, am = 0.f;
        for (int k = 0; k < 50; ++k) {
            float v = __bfloat162float(hs[k][tid]);
            aw += sc[k] * v;
            am += v;
        }
        wpool[b * 300 + tid] = aw;
        mean[b * 300 + tid]  = am * (1.f / 50.f);
    }
}

// ---------------- head (coalesced via transposed weights) ----------------
__global__ __launch_bounds__(512) void k_head(const float* __restrict__ wpool, const float* __restrict__ mean,
                                              const float* __restrict__ metal2,
                                              const float* __restrict__ wvT, const float* __restrict__ lgwT,
                                              const float* __restrict__ lgb,
                                              const float* __restrict__ ph1wT, const float* __restrict__ ph1b,
                                              const float* __restrict__ ph2w, const float* __restrict__ ph2b,
                                              float* __restrict__ out) {
    int b = blockIdx.x;
    int tid = threadIdx.x;
    __shared__ float wp_s[300], mn_s[300], f_s[256], red[512];
    if (tid < 300) { wp_s[tid] = wpool[b * 300 + tid]; mn_s[tid] = mean[b * 300 + tid]; }
    __syncthreads();
    if (tid < 256) {
        float att = 0.f, lg = 0.f;
        #pragma unroll 4
        for (int k = 0; k < 300; ++k) {
            att += wp_s[k] * wvT[k * 256 + tid];
            lg  += mn_s[k] * lgwT[k * 256 + tid];
        }
        lg = fmaxf(lg + lgb[tid], 0.f);
        f_s[tid] = fmaxf(att, 0.f) + metal2[b * 256 + tid] + lg;
    }
    __syncthreads();
    float a = ph1b[tid];
    #pragma unroll 8
    for (int k = 0; k < 256; ++k) a += f_s[k] * ph1wT[k * 512 + tid];
    float sp = fmaxf(a, 0.f) + log1pf(__expf(-fabsf(a)));   // stable softplus
    red[tid] = sp * ph2w[tid];
    __syncthreads();
    for (int s = 256; s > 0; s >>= 1) {
        if (tid < s) red[tid] += red[tid + s];
        __syncthreads();
    }
    if (tid == 0) out[b] = red[0] + ph2b[0];
}

extern "C" void kernel_launch(void* const* d_in, const int* in_sizes, int n_in,
                              void* d_out, int out_size, void* d_ws, size_t ws_size,
                              hipStream_t stream) {
    const int*   x_type   = (const int*)d_in[0];
    const float* x_feat   = (const float*)d_in[1];
    const int*   eindex   = (const int*)d_in[2];
    const float* eattr    = (const float*)d_in[3];
    const int*   mtype    = (const int*)d_in[4];
    const float* mfeat    = (const float*)d_in[5];
    const float* x_emb    = (const float*)d_in[6];
    const float* x_weight = (const float*)d_in[7];
    const float* ew1      = (const float*)d_in[8];
    const float* mlp_w    = (const float*)d_in[9];
    const float* mlp_b    = (const float*)d_in[10];
    const float* bn_g     = (const float*)d_in[11];
    const float* bn_b     = (const float*)d_in[12];
    const float* bn_rm    = (const float*)d_in[13];
    const float* bn_rv    = (const float*)d_in[14];
    const float* me1_w    = (const float*)d_in[15];
    const float* me1_b    = (const float*)d_in[16];
    const float* me2      = (const float*)d_in[17];
    const float* wq       = (const float*)d_in[18];
    const float* wk       = (const float*)d_in[19];
    const float* wv       = (const float*)d_in[20];
    const float* ml_w     = (const float*)d_in[21];
    const float* ml_b     = (const float*)d_in[22];
    const float* lg_w     = (const float*)d_in[23];
    const float* lg_b     = (const float*)d_in[24];
    const float* ph1_w    = (const float*)d_in[25];
    const float* ph1_b    = (const float*)d_in[26];
    const float* ph2_w    = (const float*)d_in[27];
    const float* ph2_b    = (const float*)d_in[28];

    char* ws = (char*)d_ws;
    size_t o = 0;
    auto alloc = [&](size_t bytes) -> void* {
        void* p = ws + o;
        o += (bytes + 255) & ~(size_t)255;
        return p;
    };
    __hip_bfloat16* h    = (__hip_bfloat16*)alloc((size_t)MPAD * LDK * 2);
    __hip_bfloat16* mh   = (__hip_bfloat16*)alloc((size_t)MPAD * LDK * 2);
    __hip_bfloat16* wb   = (__hip_bfloat16*)alloc((size_t)5 * 320 * 320 * 2);
    int*     cnt    = (int*)alloc((size_t)NNODES * 4);
    int*     offs   = (int*)alloc((size_t)(NNODES + 1) * 4);
    int*     cur    = (int*)alloc((size_t)NNODES * 4);
    int*     bsum   = (int*)alloc((size_t)64 * 4);
    EdgeRec* pack   = (EdgeRec*)alloc((size_t)NTOT * sizeof(EdgeRec));
    float*   prm    = (float*)alloc((size_t)NLAYERS * 1520 * 4);
    float*   metal2 = (float*)alloc((size_t)1000 * 256 * 4);
    float*   qk     = (float*)alloc((size_t)1024 * 320 * 4);
    float*   wpool  = (float*)alloc((size_t)1000 * 300 * 4);
    float*   meanp  = (float*)alloc((size_t)1000 * 300 * 4);
    float*   wvT    = (float*)alloc((size_t)300 * 256 * 4);
    float*   lgwT   = (float*)alloc((size_t)300 * 256 * 4);
    float*   ph1wT  = (float*)alloc((size_t)256 * 512 * 4);
    float*   me1wT  = (float*)alloc((size_t)17 * 300 * 4);
    __hip_bfloat16* mfb  = (__hip_bfloat16*)alloc((size_t)1024 * 320 * 2);
    __hip_bfloat16* wcat = (__hip_bfloat16*)alloc((size_t)512 * 320 * 2);
    __hip_bfloat16* wkTb = (__hip_bfloat16*)alloc((size_t)320 * 256 * 2);
    __hip_bfloat16* qb   = (__hip_bfloat16*)alloc((size_t)1024 * 256 * 2);
    (void)ws_size; (void)in_sizes; (void)n_in; (void)out_size;

    hipMemsetAsync(cnt, 0, (size_t)NNODES * 4, stream);
    hipMemsetAsync(cur, 0, (size_t)NNODES * 4, stream);
    hipMemsetAsync(mfb, 0, (size_t)1024 * 320 * 2, stream);

    k_cvt<<<(5 * 320 * 320 + 255) / 256, 256, 0, stream>>>(mlp_w, wb);
    k_cvt2<<<(512 * 320 + 320 * 256 + 255) / 256, 256, 0, stream>>>(wq, ml_w, wk, wcat, wkTb);
    k_trall<<<(289772 + 255) / 256, 256, 0, stream>>>(wv, lg_w, ph1_w, me1_w, wvT, lgwT, ph1wT, me1wT);
    k_init<<<(NNODES * 38 + 255) / 256, 256, 0, stream>>>(x_type, x_feat, x_emb, x_weight, h);
    k_count<<<(NTOT + 255) / 256, 256, 0, stream>>>(eindex, cnt);
    k_scan1<<<NSCAN, 1024, 0, stream>>>(cnt, offs, bsum);
    k_scan2<<<1, 64, 0, stream>>>(bsum);
    k_scan3<<<NSCAN, 1024, 0, stream>>>(offs, bsum);
    k_fill<<<(NTOT + 255) / 256, 256, 0, stream>>>(eindex, eattr, offs, cur, pack);
    {
        dim3 gp(300, NLAYERS);
        k_prep<<<gp, 64, 0, stream>>>(mlp_w, ew1, mlp_b, bn_g, bn_b, bn_rm, bn_rv, prm);
    }
    // metal path: mf -> {q, metal2} -> qk  (batched MFMA GEMMs)
    k_mf<<<(1000 * 300 + 255) / 256, 256, 0, stream>>>(mtype, mfeat, me1wT, me1_b, me2, mfb);
    {
        dim3 g1(8, 8);   // M=1024, N=512, K=320
        k_mm<<<g1, 256, 0, stream>>>(mfb, 320, wcat, 320, 320, 0, ml_b, qb, metal2, qk);
        dim3 g2(8, 5);   // M=1024, N=320, K=256
        k_mm<<<g2, 256, 0, stream>>>(qb, 256, wkTb, 256, 256, 1, ml_b, qb, metal2, qk);
    }

    for (int l = 0; l < NLAYERS; ++l) {
        k_gemm<<<784, 256, 0, stream>>>(h, wb + (size_t)l * 102400, mh);
        int aggr_grid = (NNODES + 4 * NPW - 1) / (4 * NPW);
        k_aggr<<<aggr_grid, 256, 0, stream>>>(mh, pack, offs, prm + (size_t)l * 1520, h,
                                              (l < NLAYERS - 1) ? 1 : 0);
    }

    k_pool<<<1000, 320, 0, stream>>>(h, qk, wpool, meanp);
    k_head<<<1000, 512, 0, stream>>>(wpool, meanp, metal2, wvT, lgwT, lg_b,
                                     ph1wT, ph1_b, ph2_w, ph2_b, (float*)d_out);
}

// Round 12
// 566.826 us; speedup vs baseline: 1.5656x; 1.0803x over previous
//
#include <hip/hip_runtime.h>
#include <hip/hip_bf16.h>
#include <math.h>

#define NNODES  50000
#define NEDGES  200000
#define NTOT    250000      // E + N self loops
#define EMB     300
#define LDK     320         // padded K stride (bf16 h / mh / weights)
#define MPAD    50048       // 391 * 128 (GEMM M padding)
#define NLAYERS 5
#define NSCAN   49          // ceil(NNODES / 1024)
#define NPW     4           // nodes per wave in k_aggr (amortize prm prologue)

struct EdgeRec { int r; float c0, c1; };

typedef __attribute__((ext_vector_type(8))) short short8;
typedef __attribute__((ext_vector_type(4))) float floatx4;

__device__ inline void gll16(const void* g, void* s) {
    __builtin_amdgcn_global_load_lds((const __attribute__((address_space(1))) unsigned*)g,
                                     (__attribute__((address_space(3))) unsigned*)s, 16, 0, 0);
}

// ---------------- weight convert: wb[l][320][320] = bf16(mlp_w[l][300][300]) zero-padded ----------------
__global__ void k_cvt(const float* __restrict__ w, __hip_bfloat16* __restrict__ wb) {
    int idx = blockIdx.x * 256 + threadIdx.x;
    if (idx >= 5 * 320 * 320) return;
    int l = idx / 102400, r = idx % 102400, n = r / 320, k = r % 320;
    float v = (n < 300 && k < 300) ? w[l * 90000 + n * 300 + k] : 0.f;
    wb[idx] = __float2bfloat16(v);
}

// ---------------- metal-path weight packs: wcat[512][320] = [wq; ml_w], wkTb[320][256] = wk^T ----------------
__global__ void k_cvt2(const float* __restrict__ wq, const float* __restrict__ ml_w,
                       const float* __restrict__ wk,
                       __hip_bfloat16* __restrict__ wcat, __hip_bfloat16* __restrict__ wkTb) {
    int idx = blockIdx.x * 256 + threadIdx.x;
    if (idx < 512 * 320) {
        int r = idx / 320, k = idx % 320;
        float v = 0.f;
        if (k < 300) v = (r < 256) ? wq[r * 300 + k] : ml_w[(r - 256) * 300 + k];
        wcat[idx] = __float2bfloat16(v);
        return;
    }
    idx -= 512 * 320;
    if (idx < 320 * 256) {
        int c = idx / 256, j = idx % 256;
        float v = (c < 300) ? wk[j * 300 + c] : 0.f;
        wkTb[idx] = __float2bfloat16(v);
    }
}

// ---------------- init/head weight packs ----------------
// xfb[50048][32]=bf16(x_feat) K-pad; xwTb[320][32]=bf16(x_weight^T); wvB/lgwB[256][320];
// ph1wb[512][256]; me1wT fp32 transpose
__global__ void k_cvt3(const float* __restrict__ xf, const float* __restrict__ xw,
                       const float* __restrict__ wv, const float* __restrict__ lg_w,
                       const float* __restrict__ ph1_w, const float* __restrict__ me1_w,
                       __hip_bfloat16* __restrict__ xfb, __hip_bfloat16* __restrict__ xwTb,
                       __hip_bfloat16* __restrict__ wvB, __hip_bfloat16* __restrict__ lgwB,
                       __hip_bfloat16* __restrict__ ph1wb, float* __restrict__ me1wT) {
    int idx = blockIdx.x * 256 + threadIdx.x;
    if (idx < 1601536) {
        int n = idx >> 5, k = idx & 31;
        xfb[idx] = __float2bfloat16((n < 50000 && k < 16) ? xf[n * 16 + k] : 0.f);
        return;
    }
    idx -= 1601536;
    if (idx < 10240) {
        int n = idx >> 5, k = idx & 31;
        xwTb[idx] = __float2bfloat16((n < 300 && k < 16) ? xw[k * 300 + n] : 0.f);
        return;
    }
    idx -= 10240;
    if (idx < 81920) { int r = idx / 320, k = idx % 320;
        wvB[idx] = __float2bfloat16((k < 300) ? wv[r * 300 + k] : 0.f); return; }
    idx -= 81920;
    if (idx < 81920) { int r = idx / 320, k = idx % 320;
        lgwB[idx] = __float2bfloat16((k < 300) ? lg_w[r * 300 + k] : 0.f); return; }
    idx -= 81920;
    if (idx < 131072) { ph1wb[idx] = __float2bfloat16(ph1_w[idx]); return; }
    idx -= 131072;
    if (idx < 5100) { int r = idx / 17, c = idx % 17; me1wT[c * 300 + r] = me1_w[idx]; }
}

// ---------------- mf = me1b + me2[mt] + mfeat @ me1wT, bf16 [1024,320] (pads pre-zeroed) ----------------
__global__ __launch_bounds__(256) void k_mf(const int* __restrict__ mt, const float* __restrict__ mfeat,
                                            const float* __restrict__ me1wT, const float* __restrict__ me1b,
                                            const float* __restrict__ me2,
                                            __hip_bfloat16* __restrict__ mfb) {
    int idx = blockIdx.x * 256 + threadIdx.x;
    if (idx >= 1000 * 300) return;
    int g = idx / 300, c = idx % 300;
    float v = me1b[c] + me2[(size_t)mt[g] * 300 + c];
    #pragma unroll
    for (int k = 0; k < 17; ++k) v += mfeat[g * 17 + k] * me1wT[k * 300 + c];
    mfb[(size_t)g * 320 + c] = __float2bfloat16(v);
}

// ---------------- generic 128x64 MFMA GEMM for metal path (modes 0/1) ----------------
__global__ __launch_bounds__(256) void k_mm(const __hip_bfloat16* __restrict__ A, int lda,
                                            const __hip_bfloat16* __restrict__ B, int ldb,
                                            int K, int mode,
                                            const float* __restrict__ mlb,
                                            __hip_bfloat16* __restrict__ qb,
                                            float* __restrict__ metal2,
                                            float* __restrict__ qkout) {
    __shared__ __hip_bfloat16 As[128 * 32];
    __shared__ __hip_bfloat16 Bs[64 * 32];
    int tid = threadIdx.x, lane = tid & 63, w = tid >> 6;
    int row0 = blockIdx.x * 128, col0 = blockIdx.y * 64;

    floatx4 acc[2][4];
    #pragma unroll
    for (int i = 0; i < 2; ++i)
        #pragma unroll
        for (int j = 0; j < 4; ++j) acc[i][j] = (floatx4){0.f, 0.f, 0.f, 0.f};

    const __hip_bfloat16* ga0 = A + (size_t)(row0 + w * 32 + (lane >> 2)) * lda + (lane & 3) * 8;
    const __hip_bfloat16* ga1 = ga0 + (size_t)16 * lda;
    const __hip_bfloat16* gb  = B + (size_t)(col0 + w * 16 + (lane >> 2)) * ldb + (lane & 3) * 8;
    __hip_bfloat16* sa0 = &As[(w * 32) * 32];
    __hip_bfloat16* sa1 = &As[(w * 32 + 16) * 32];
    __hip_bfloat16* sb  = &Bs[(w * 16) * 32];

    int m15 = lane & 15, kof = (lane >> 4) * 8;

    for (int k0 = 0; k0 < K; k0 += 32) {
        __syncthreads();
        gll16(ga0 + k0, sa0);
        gll16(ga1 + k0, sa1);
        gll16(gb  + k0, sb);
        __syncthreads();

        short8 a[2], b[4];
        a[0] = *(const short8*)&As[(w * 32 +      m15) * 32 + kof];
        a[1] = *(const short8*)&As[(w * 32 + 16 + m15) * 32 + kof];
        #pragma unroll
        for (int nt = 0; nt < 4; ++nt)
            b[nt] = *(const short8*)&Bs[(nt * 16 + m15) * 32 + kof];

        #pragma unroll
        for (int mt = 0; mt < 2; ++mt)
            #pragma unroll
            for (int nt = 0; nt < 4; ++nt)
                acc[mt][nt] = __builtin_amdgcn_mfma_f32_16x16x32_bf16(a[mt], b[nt], acc[mt][nt], 0, 0, 0);
    }

    int rbase = row0 + w * 32 + (lane >> 4) * 4;
    #pragma unroll
    for (int mt = 0; mt < 2; ++mt)
        #pragma unroll
        for (int i = 0; i < 4; ++i) {
            int gr = rbase + mt * 16 + i;
            #pragma unroll
            for (int nt = 0; nt < 4; ++nt) {
                int gc = col0 + nt * 16 + m15;
                float v = acc[mt][nt][i];
                if (mode == 0) {
                    if (gc < 256) qb[(size_t)gr * 256 + gc] = __float2bfloat16(v);
                    else if (gr < 1000) metal2[(size_t)gr * 256 + (gc - 256)] = fmaxf(v + mlb[gc - 256], 0.f);
                } else {
                    if (gc < 300 && gr < 1000) qkout[(size_t)gr * 320 + gc] = v;
                }
            }
        }
}

// ---------------- generic 128x64 MFMA GEMM, raw fp32 store (head path) ----------------
__global__ __launch_bounds__(256) void k_mm2(const __hip_bfloat16* __restrict__ A, int lda,
                                             const __hip_bfloat16* __restrict__ B, int ldb,
                                             int K, float* __restrict__ C, int ldc) {
    __shared__ __hip_bfloat16 As[128 * 32];
    __shared__ __hip_bfloat16 Bs[64 * 32];
    int tid = threadIdx.x, lane = tid & 63, w = tid >> 6;
    int row0 = blockIdx.x * 128, col0 = blockIdx.y * 64;

    floatx4 acc[2][4];
    #pragma unroll
    for (int i = 0; i < 2; ++i)
        #pragma unroll
        for (int j = 0; j < 4; ++j) acc[i][j] = (floatx4){0.f, 0.f, 0.f, 0.f};

    const __hip_bfloat16* ga0 = A + (size_t)(row0 + w * 32 + (lane >> 2)) * lda + (lane & 3) * 8;
    const __hip_bfloat16* ga1 = ga0 + (size_t)16 * lda;
    const __hip_bfloat16* gb  = B + (size_t)(col0 + w * 16 + (lane >> 2)) * ldb + (lane & 3) * 8;
    __hip_bfloat16* sa0 = &As[(w * 32) * 32];
    __hip_bfloat16* sa1 = &As[(w * 32 + 16) * 32];
    __hip_bfloat16* sb  = &Bs[(w * 16) * 32];

    int m15 = lane & 15, kof = (lane >> 4) * 8;

    for (int k0 = 0; k0 < K; k0 += 32) {
        __syncthreads();
        gll16(ga0 + k0, sa0);
        gll16(ga1 + k0, sa1);
        gll16(gb  + k0, sb);
        __syncthreads();

        short8 a[2], b[4];
        a[0] = *(const short8*)&As[(w * 32 +      m15) * 32 + kof];
        a[1] = *(const short8*)&As[(w * 32 + 16 + m15) * 32 + kof];
        #pragma unroll
        for (int nt = 0; nt < 4; ++nt)
            b[nt] = *(const short8*)&Bs[(nt * 16 + m15) * 32 + kof];

        #pragma unroll
        for (int mt = 0; mt < 2; ++mt)
            #pragma unroll
            for (int nt = 0; nt < 4; ++nt)
                acc[mt][nt] = __builtin_amdgcn_mfma_f32_16x16x32_bf16(a[mt], b[nt], acc[mt][nt], 0, 0, 0);
    }

    int rbase = row0 + w * 32 + (lane >> 4) * 4;
    #pragma unroll
    for (int mt = 0; mt < 2; ++mt)
        #pragma unroll
        for (int i = 0; i < 4; ++i) {
            int gr = rbase + mt * 16 + i;
            #pragma unroll
            for (int nt = 0; nt < 4; ++nt)
                C[(size_t)gr * ldc + col0 + nt * 16 + m15] = acc[mt][nt][i];
        }
}

// ---------------- node init as MFMA GEMM: h = bf16(xemb[xt] + xfb @ xwTb^T), K=32 (one iter) ----------------
__global__ __launch_bounds__(256) void k_initg(const __hip_bfloat16* __restrict__ A,
                                               const __hip_bfloat16* __restrict__ B,
                                               const int* __restrict__ xt,
                                               const float* __restrict__ xemb,
                                               __hip_bfloat16* __restrict__ h) {
    int b = blockIdx.x;
    int rowblk = (b >> 4) * 8 + (b & 7);
    if (rowblk >= 391) return;
    int row0 = rowblk * 128;
    int col0 = ((b >> 3) & 1) * 160;

    __shared__ __hip_bfloat16 As[128 * 32];
    __shared__ __hip_bfloat16 Bs[160 * 32];
    int tid = threadIdx.x;
    int lane = tid & 63, w = tid >> 6;

    floatx4 acc[2][10];
    #pragma unroll
    for (int i = 0; i < 2; ++i)
        #pragma unroll
        for (int j = 0; j < 10; ++j) acc[i][j] = (floatx4){0.f, 0.f, 0.f, 0.f};

    const __hip_bfloat16* ga0 = A + (size_t)(row0 + w * 32 + (lane >> 2)) * 32 + (lane & 3) * 8;
    const __hip_bfloat16* ga1 = ga0 + (size_t)16 * 32;
    __hip_bfloat16* sa0 = &As[(w * 32) * 32];
    __hip_bfloat16* sa1 = &As[(w * 32 + 16) * 32];
    int brow0 = (w < 2) ? w * 48 : 96 + (w - 2) * 32;
    int nb = (w < 2) ? 3 : 2;
    const __hip_bfloat16* gb = B + (size_t)(col0 + brow0 + (lane >> 2)) * 32 + (lane & 3) * 8;
    __hip_bfloat16* sb = &Bs[brow0 * 32];

    int m15 = lane & 15, kof = (lane >> 4) * 8;

    gll16(ga0, sa0);
    gll16(ga1, sa1);
    for (int i = 0; i < nb; ++i)
        gll16(gb + (size_t)i * 16 * 32, sb + i * 16 * 32);
    __syncthreads();

    short8 a[2], bb[10];
    a[0] = *(const short8*)&As[(w * 32 +      m15) * 32 + kof];
    a[1] = *(const short8*)&As[(w * 32 + 16 + m15) * 32 + kof];
    #pragma unroll
    for (int nt = 0; nt < 10; ++nt)
        bb[nt] = *(const short8*)&Bs[(nt * 16 + m15) * 32 + kof];

    #pragma unroll
    for (int mt = 0; mt < 2; ++mt)
        #pragma unroll
        for (int nt = 0; nt < 10; ++nt)
            acc[mt][nt] = __builtin_amdgcn_mfma_f32_16x16x32_bf16(a[mt], bb[nt], acc[mt][nt], 0, 0, 0);

    int rbase = row0 + w * 32 + (lane >> 4) * 4;
    #pragma unroll
    for (int mt = 0; mt < 2; ++mt)
        #pragma unroll
        for (int i = 0; i < 4; ++i) {
            int gr = rbase + mt * 16 + i;
            if (gr < NNODES) {
                const float* er = xemb + (size_t)xt[gr] * 300;
                #pragma unroll
                for (int nt = 0; nt < 10; ++nt) {
                    int gc = col0 + nt * 16 + m15;
                    if (gc < 300)
                        h[(size_t)gr * LDK + gc] = __float2bfloat16(acc[mt][nt][i] + er[gc]);
                }
            }
        }
}

// ---------------- CSR build ----------------
__global__ void k_count(const int* __restrict__ ei, int* __restrict__ cnt) {
    int e = blockIdx.x * blockDim.x + threadIdx.x;
    if (e >= NTOT) return;
    int c = (e < NEDGES) ? ei[NEDGES + e] : (e - NEDGES);
    atomicAdd(&cnt[c], 1);
}

__global__ __launch_bounds__(1024) void k_scan1(const int* __restrict__ cnt, int* __restrict__ off,
                                                int* __restrict__ bsum) {
    int tid = threadIdx.x;
    int gid = blockIdx.x * 1024 + tid;
    int lane = tid & 63, wv = tid >> 6;
    int v = (gid < NNODES) ? cnt[gid] : 0;
    int x = v;
    #pragma unroll
    for (int s = 1; s < 64; s <<= 1) {
        int t = __shfl_up(x, s, 64);
        if (lane >= s) x += t;
    }
    __shared__ int wsum[16];
    if (lane == 63) wsum[wv] = x;
    __syncthreads();
    if (wv == 0) {
        int w = (lane < 16) ? wsum[lane] : 0;
        #pragma unroll
        for (int s = 1; s < 16; s <<= 1) {
            int t = __shfl_up(w, s, 64);
            if (lane >= s) w += t;
        }
        if (lane < 16) wsum[lane] = w;
    }
    __syncthreads();
    int base = (wv > 0) ? wsum[wv - 1] : 0;
    int incl = x + base;
    if (gid < NNODES) off[gid] = incl - v;
    if (tid == 1023) bsum[blockIdx.x] = incl;
}

__global__ __launch_bounds__(64) void k_scan2(int* __restrict__ bsum) {
    int lane = threadIdx.x;
    int v = (lane < NSCAN) ? bsum[lane] : 0;
    int x = v;
    #pragma unroll
    for (int s = 1; s < 64; s <<= 1) {
        int t = __shfl_up(x, s, 64);
        if (lane >= s) x += t;
    }
    if (lane < NSCAN) bsum[lane] = x - v;
}

__global__ __launch_bounds__(1024) void k_scan3(int* __restrict__ off, const int* __restrict__ bsum) {
    int gid = blockIdx.x * 1024 + threadIdx.x;
    if (gid < NNODES) off[gid] += bsum[blockIdx.x];
    if (gid == 0) off[NNODES] = NTOT;
}

__global__ void k_fill(const int* __restrict__ ei, const float* __restrict__ ea,
                       const int* __restrict__ off, int* __restrict__ cur,
                       EdgeRec* __restrict__ pack) {
    int e = blockIdx.x * blockDim.x + threadIdx.x;
    if (e >= NTOT) return;
    int r, c; float c0, c1;
    if (e < NEDGES) { r = ei[e]; c = ei[NEDGES + e]; c0 = ea[2 * e]; c1 = ea[2 * e + 1]; }
    else            { r = c = e - NEDGES; c0 = 0.f; c1 = 4.f; }
    int p = atomicAdd(&cur[c], 1);
    EdgeRec rec; rec.r = r; rec.c0 = c0; rec.c1 = c1;
    pack[off[c] + p] = rec;
}

// ---------------- per-layer precompute, all layers in one launch ----------------
__global__ __launch_bounds__(64) void k_prep(const float* __restrict__ mlp_w, const float* __restrict__ ew1,
                                             const float* __restrict__ mlp_b, const float* __restrict__ bn_g,
                                             const float* __restrict__ bn_b, const float* __restrict__ bn_rm,
                                             const float* __restrict__ bn_rv, float* __restrict__ prm) {
    int j = blockIdx.x, l = blockIdx.y;
    int lane = threadIdx.x;
    const float* W  = mlp_w + (size_t)l * 90000 + (size_t)j * 300;
    const float* ew = ew1 + l * 600;
    float a0 = 0.f, a1 = 0.f;
    #pragma unroll
    for (int i = 0; i < 5; ++i) {
        int k = lane + i * 64;
        if (k < 300) {
            float w = W[k];
            a0 += w * ew[k];
            a1 += w * ew[300 + k];
        }
    }
    #pragma unroll
    for (int s = 32; s > 0; s >>= 1) { a0 += __shfl_xor(a0, s, 64); a1 += __shfl_xor(a1, s, 64); }
    if (lane == 0) {
        float* p = prm + l * 1520;
        p[j] = a0;
        p[304 + j] = a1;
        p[608 + j] = mlp_b[l * 300 + j];
        float sc = bn_g[l * 300 + j] * rsqrtf(bn_rv[l * 300 + j] + 1e-5f);
        p[912 + j] = sc;
        p[1216 + j] = bn_b[l * 300 + j] - bn_rm[l * 300 + j] * sc;
    }
}

// ---------------- MFMA GEMM (layers): LDS-staged 128x160 block, XCD-swizzled grid ----------------
__global__ __launch_bounds__(256) void k_gemm(const __hip_bfloat16* __restrict__ A,
                                              const __hip_bfloat16* __restrict__ B,
                                              __hip_bfloat16* __restrict__ C) {
    int b = blockIdx.x;
    int rowblk = (b >> 4) * 8 + (b & 7);
    if (rowblk >= 391) return;
    int row0 = rowblk * 128;
    int col0 = ((b >> 3) & 1) * 160;

    __shared__ __hip_bfloat16 As[128 * 32];
    __shared__ __hip_bfloat16 Bs[160 * 32];
    int tid = threadIdx.x;
    int lane = tid & 63, w = tid >> 6;

    floatx4 acc[2][10];
    #pragma unroll
    for (int i = 0; i < 2; ++i)
        #pragma unroll
        for (int j = 0; j < 10; ++j) acc[i][j] = (floatx4){0.f, 0.f, 0.f, 0.f};

    const __hip_bfloat16* ga0 = A + (size_t)(row0 + w * 32 + (lane >> 2)) * LDK + (lane & 3) * 8;
    const __hip_bfloat16* ga1 = ga0 + (size_t)16 * LDK;
    __hip_bfloat16* sa0 = &As[(w * 32) * 32];
    __hip_bfloat16* sa1 = &As[(w * 32 + 16) * 32];
    int brow0 = (w < 2) ? w * 48 : 96 + (w - 2) * 32;
    int nb = (w < 2) ? 3 : 2;
    const __hip_bfloat16* gb = B + (size_t)(col0 + brow0 + (lane >> 2)) * LDK + (lane & 3) * 8;
    __hip_bfloat16* sb = &Bs[brow0 * 32];

    int m15 = lane & 15, kof = (lane >> 4) * 8;

    for (int k0 = 0; k0 < LDK; k0 += 32) {
        __syncthreads();
        gll16(ga0 + k0, sa0);
        gll16(ga1 + k0, sa1);
        for (int i = 0; i < nb; ++i)
            gll16(gb + (size_t)i * 16 * LDK + k0, sb + i * 16 * 32);
        __syncthreads();

        short8 a[2], bb[10];
        a[0] = *(const short8*)&As[(w * 32 +      m15) * 32 + kof];
        a[1] = *(const short8*)&As[(w * 32 + 16 + m15) * 32 + kof];
        #pragma unroll
        for (int nt = 0; nt < 10; ++nt)
            bb[nt] = *(const short8*)&Bs[(nt * 16 + m15) * 32 + kof];

        #pragma unroll
        for (int mt = 0; mt < 2; ++mt)
            #pragma unroll
            for (int nt = 0; nt < 10; ++nt)
                acc[mt][nt] = __builtin_amdgcn_mfma_f32_16x16x32_bf16(a[mt], bb[nt], acc[mt][nt], 0, 0, 0);
    }

    int rbase = row0 + w * 32 + (lane >> 4) * 4;
    #pragma unroll
    for (int mt = 0; mt < 2; ++mt)
        #pragma unroll
        for (int i = 0; i < 4; ++i) {
            long gr = rbase + mt * 16 + i;
            #pragma unroll
            for (int nt = 0; nt < 10; ++nt)
                C[gr * LDK + col0 + nt * 16 + m15] = __float2bfloat16(acc[mt][nt][i]);
        }
}

// ---------------- aggregate: wave handles NPW sequential nodes (prm prologue amortized) ----------------
__global__ __launch_bounds__(256) void k_aggr(const __hip_bfloat16* __restrict__ mh,
                                              const EdgeRec* __restrict__ pack,
                                              const int* __restrict__ off, const float* __restrict__ prm,
                                              __hip_bfloat16* __restrict__ h, int do_relu) {
    int wave = threadIdx.x >> 6;
    int lane = threadIdx.x & 63;
    int n0 = (blockIdx.x * 4 + wave) * NPW;
    if (n0 >= NNODES) return;

    float u0[3][2], u1[3][2], bv[3][2], sc[3][2], sh[3][2];
    #pragma unroll
    for (int i = 0; i < 3; ++i) {
        int j = 2 * lane + 128 * i;
        #pragma unroll
        for (int t = 0; t < 2; ++t) {
            bool ok = (j + t) < 300;
            u0[i][t] = ok ? prm[j + t]        : 0.f;
            u1[i][t] = ok ? prm[304 + j + t]  : 0.f;
            bv[i][t] = ok ? prm[608 + j + t]  : 0.f;
            sc[i][t] = ok ? prm[912 + j + t]  : 0.f;
            sh[i][t] = ok ? prm[1216 + j + t] : 0.f;
        }
    }

    int nend = (n0 + NPW < NNODES) ? n0 + NPW : NNODES;
    for (int n = n0; n < nend; ++n) {
        float acc[3][2];
        #pragma unroll
        for (int i = 0; i < 3; ++i) { acc[i][0] = 0.f; acc[i][1] = 0.f; }
        int p0 = off[n], p1 = off[n + 1];
        int p = p0;
        for (; p + 1 < p1; p += 2) {
            EdgeRec e0 = pack[p], e1 = pack[p + 1];
            const __hip_bfloat16* b0 = mh + (size_t)e0.r * LDK;
            const __hip_bfloat16* b1 = mh + (size_t)e1.r * LDK;
            __hip_bfloat162 hv0[3], hv1[3];
            #pragma unroll
            for (int i = 0; i < 3; ++i) {
                int j = 2 * lane + 128 * i;
                if (j < 300) {
                    hv0[i] = *(const __hip_bfloat162*)&b0[j];
                    hv1[i] = *(const __hip_bfloat162*)&b1[j];
                }
            }
            #pragma unroll
            for (int i = 0; i < 3; ++i) {
                int j = 2 * lane + 128 * i;
                if (j < 300) {
                    acc[i][0] += fmaxf(__bfloat162float(hv0[i].x) + e0.c0 * u0[i][0] + e0.c1 * u1[i][0] + bv[i][0], 0.f);
                    acc[i][1] += fmaxf(__bfloat162float(hv0[i].y) + e0.c0 * u0[i][1] + e0.c1 * u1[i][1] + bv[i][1], 0.f);
                    acc[i][0] += fmaxf(__bfloat162float(hv1[i].x) + e1.c0 * u0[i][0] + e1.c1 * u1[i][0] + bv[i][0], 0.f);
                    acc[i][1] += fmaxf(__bfloat162float(hv1[i].y) + e1.c0 * u0[i][1] + e1.c1 * u1[i][1] + bv[i][1], 0.f);
                }
            }
        }
        if (p < p1) {
            EdgeRec e0 = pack[p];
            const __hip_bfloat16* b0 = mh + (size_t)e0.r * LDK;
            #pragma unroll
            for (int i = 0; i < 3; ++i) {
                int j = 2 * lane + 128 * i;
                if (j < 300) {
                    __hip_bfloat162 hv = *(const __hip_bfloat162*)&b0[j];
                    acc[i][0] += fmaxf(__bfloat162float(hv.x) + e0.c0 * u0[i][0] + e0.c1 * u1[i][0] + bv[i][0], 0.f);
                    acc[i][1] += fmaxf(__bfloat162float(hv.y) + e0.c0 * u0[i][1] + e0.c1 * u1[i][1] + bv[i][1], 0.f);
                }
            }
        }
        #pragma unroll
        for (int i = 0; i < 3; ++i) {
            int j = 2 * lane + 128 * i;
            if (j < 300) {
                float v0 = acc[i][0] * sc[i][0] + sh[i][0];
                float v1 = acc[i][1] * sc[i][1] + sh[i][1];
                if (do_relu) { v0 = fmaxf(v0, 0.f); v1 = fmaxf(v1, 0.f); }
                __hip_bfloat162 o;
                o.x = __float2bfloat16(v0);
                o.y = __float2bfloat16(v1);
                *(__hip_bfloat162*)&h[(size_t)n * LDK + j] = o;
            }
        }
    }
}

// ---------------- attention pool (LDS-cached h tile) -> bf16 wpool/mean [1024x320] ----------------
__global__ __launch_bounds__(320) void k_pool(const __hip_bfloat16* __restrict__ h, const float* __restrict__ qk,
                                              __hip_bfloat16* __restrict__ wpb, __hip_bfloat16* __restrict__ mnb) {
    int b = blockIdx.x;
    int tid = threadIdx.x;
    int wave = tid >> 6, lane = tid & 63;
    __shared__ float qk_s[300];
    __shared__ float sc[50];
    __shared__ __hip_bfloat16 hs[50][304];
    if (tid < 300) qk_s[tid] = qk[(size_t)b * 320 + tid];
    __syncthreads();
    for (int k = wave; k < 50; k += 5) {
        const __hip_bfloat16* hp = h + (long)(b * 50 + k) * LDK;
        float partial = 0.f;
        #pragma unroll
        for (int i = 0; i < 5; ++i) {
            int j = lane + i * 64;
            if (j < 300) {
                __hip_bfloat16 hv = hp[j];
                hs[k][j] = hv;
                partial += __bfloat162float(hv) * qk_s[j];
            }
        }
        #pragma unroll
        for (int s = 32; s > 0; s >>= 1) partial += __shfl_xor(partial, s, 64);
        if (lane == 0) sc[k] = partial * (1.f / 16.f);
    }
    __syncthreads();
    if (tid == 0) {
        float mx = sc[0];
        for (int k = 1; k < 50; ++k) mx = fmaxf(mx, sc[k]);
        float s = 0.f;
        for (int k = 0; k < 50; ++k) { float e = __expf(sc[k] - mx); sc[k] = e; s += e; }
        float inv = 1.f / s;
        for (int k = 0; k < 50; ++k) sc[k] *= inv;
    }
    __syncthreads();
    if (tid < 300) {
        float aw = 0.f, am = 0.f;
        for (int k = 0; k < 50; ++k) {
            float v = __bfloat162float(hs[k][tid]);
            aw += sc[k] * v;
            am += v;
        }
        wpb[(size_t)b * 320 + tid] = __float2bfloat16(aw);
        mnb[(size_t)b * 320 + tid] = __float2bfloat16(am * (1.f / 50.f));
    }
}

// ---------------- combine: f = relu(att) + metal2 + relu(lig + lg_b), bf16 ----------------
__global__ void k_comb(const float* __restrict__ attb, const float* __restrict__ ligb,
                       const float* __restrict__ metal2, const float* __restrict__ lg_bias,
                       __hip_bfloat16* __restrict__ fb) {
    int idx = blockIdx.x * 256 + threadIdx.x;
    if (idx >= 1000 * 256) return;
    int c = idx & 255;
    float f = fmaxf(attb[idx], 0.f) + metal2[idx] + fmaxf(ligb[idx] + lg_bias[c], 0.f);
    fb[idx] = __float2bfloat16(f);
}

// ---------------- out: softplus(a + ph1b) . ph2w + ph2b ----------------
__global__ __launch_bounds__(512) void k_out(const float* __restrict__ a2, const float* __restrict__ ph1b,
                                             const float* __restrict__ ph2w, const float* __restrict__ ph2b,
                                             float* __restrict__ out) {
    int b = blockIdx.x, t = threadIdx.x;
    int lane = t & 63, wv = t >> 6;
    float a = a2[(size_t)b * 512 + t] + ph1b[t];
    float sp = fmaxf(a, 0.f) + log1pf(__expf(-fabsf(a)));
    float r = sp * ph2w[t];
    #pragma unroll
    for (int s = 32; s > 0; s >>= 1) r += __shfl_xor(r, s, 64);
    __shared__ float red[8];
    if (lane == 0) red[wv] = r;
    __syncthreads();
    if (t == 0) {
        float s = 0.f;
        #pragma unroll
        for (int i = 0; i < 8; ++i) s += red[i];
        out[b] = s + ph2b[0];
    }
}

extern "C" void kernel_launch(void* const* d_in, const int* in_sizes, int n_in,
                              void* d_out, int out_size, void* d_ws, size_t ws_size,
                              hipStream_t stream) {
    const int*   x_type   = (const int*)d_in[0];
    const float* x_feat   = (const float*)d_in[1];
    const int*   eindex   = (const int*)d_in[2];
    const float* eattr    = (const float*)d_in[3];
    const int*   mtype    = (const int*)d_in[4];
    const float* mfeat    = (const float*)d_in[5];
    const float* x_emb    = (const float*)d_in[6];
    const float* x_weight = (const float*)d_in[7];
    const float* ew1      = (const float*)d_in[8];
    const float* mlp_w    = (const float*)d_in[9];
    const float* mlp_b    = (const float*)d_in[10];
    const float* bn_g     = (const float*)d_in[11];
    const float* bn_b     = (const float*)d_in[12];
    const float* bn_rm    = (const float*)d_in[13];
    const float* bn_rv    = (const float*)d_in[14];
    const float* me1_w    = (const float*)d_in[15];
    const float* me1_b    = (const float*)d_in[16];
    const float* me2      = (const float*)d_in[17];
    const float* wq       = (const float*)d_in[18];
    const float* wk       = (const float*)d_in[19];
    const float* wv       = (const float*)d_in[20];
    const float* ml_w     = (const float*)d_in[21];
    const float* ml_b     = (const float*)d_in[22];
    const float* lg_w     = (const float*)d_in[23];
    const float* lg_b     = (const float*)d_in[24];
    const float* ph1_w    = (const float*)d_in[25];
    const float* ph1_b    = (const float*)d_in[26];
    const float* ph2_w    = (const float*)d_in[27];
    const float* ph2_b    = (const float*)d_in[28];

    char* ws = (char*)d_ws;
    size_t o = 0;
    auto alloc = [&](size_t bytes) -> void* {
        void* p = ws + o;
        o += (bytes + 255) & ~(size_t)255;
        return p;
    };
    __hip_bfloat16* h    = (__hip_bfloat16*)alloc((size_t)MPAD * LDK * 2);
    __hip_bfloat16* mh   = (__hip_bfloat16*)alloc((size_t)MPAD * LDK * 2);
    __hip_bfloat16* wb   = (__hip_bfloat16*)alloc((size_t)5 * 320 * 320 * 2);
    int*     cnt    = (int*)alloc((size_t)NNODES * 4);
    int*     offs   = (int*)alloc((size_t)(NNODES + 1) * 4);
    int*     cur    = (int*)alloc((size_t)NNODES * 4);
    int*     bsum   = (int*)alloc((size_t)64 * 4);
    EdgeRec* pack   = (EdgeRec*)alloc((size_t)NTOT * sizeof(EdgeRec));
    float*   prm    = (float*)alloc((size_t)NLAYERS * 1520 * 4);
    float*   metal2 = (float*)alloc((size_t)1000 * 256 * 4);
    float*   qk     = (float*)alloc((size_t)1024 * 320 * 4);
    float*   me1wT  = (float*)alloc((size_t)17 * 300 * 4);
    __hip_bfloat16* mfb  = (__hip_bfloat16*)alloc((size_t)1024 * 320 * 2);
    __hip_bfloat16* wcat = (__hip_bfloat16*)alloc((size_t)512 * 320 * 2);
    __hip_bfloat16* wkTb = (__hip_bfloat16*)alloc((size_t)320 * 256 * 2);
    __hip_bfloat16* qb   = (__hip_bfloat16*)alloc((size_t)1024 * 256 * 2);
    __hip_bfloat16* xfb  = (__hip_bfloat16*)alloc((size_t)MPAD * 32 * 2);
    __hip_bfloat16* xwTb = (__hip_bfloat16*)alloc((size_t)320 * 32 * 2);
    __hip_bfloat16* wvB  = (__hip_bfloat16*)alloc((size_t)256 * 320 * 2);
    __hip_bfloat16* lgwB = (__hip_bfloat16*)alloc((size_t)256 * 320 * 2);
    __hip_bfloat16* ph1wb= (__hip_bfloat16*)alloc((size_t)512 * 256 * 2);
    __hip_bfloat16* wpb  = (__hip_bfloat16*)alloc((size_t)1024 * 320 * 2);
    __hip_bfloat16* mnb  = (__hip_bfloat16*)alloc((size_t)1024 * 320 * 2);
    float*   attb   = (float*)alloc((size_t)1024 * 256 * 4);
    float*   ligb   = (float*)alloc((size_t)1024 * 256 * 4);
    __hip_bfloat16* fb = (__hip_bfloat16*)alloc((size_t)1024 * 256 * 2);
    float*   a2     = (float*)alloc((size_t)1024 * 512 * 4);
    (void)ws_size; (void)in_sizes; (void)n_in; (void)out_size;

    hipMemsetAsync(cnt, 0, (size_t)NNODES * 4, stream);
    hipMemsetAsync(cur, 0, (size_t)NNODES * 4, stream);
    hipMemsetAsync(mfb, 0, (size_t)1024 * 320 * 2, stream);

    k_cvt<<<(5 * 320 * 320 + 255) / 256, 256, 0, stream>>>(mlp_w, wb);
    k_cvt2<<<(512 * 320 + 320 * 256 + 255) / 256, 256, 0, stream>>>(wq, ml_w, wk, wcat, wkTb);
    k_cvt3<<<(1911788 + 255) / 256, 256, 0, stream>>>(x_feat, x_weight, wv, lg_w, ph1_w, me1_w,
                                                      xfb, xwTb, wvB, lgwB, ph1wb, me1wT);
    k_initg<<<784, 256, 0, stream>>>(xfb, xwTb, x_type, x_emb, h);
    k_count<<<(NTOT + 255) / 256, 256, 0, stream>>>(eindex, cnt);
    k_scan1<<<NSCAN, 1024, 0, stream>>>(cnt, offs, bsum);
    k_scan2<<<1, 64, 0, stream>>>(bsum);
    k_scan3<<<NSCAN, 1024, 0, stream>>>(offs, bsum);
    k_fill<<<(NTOT + 255) / 256, 256, 0, stream>>>(eindex, eattr, offs, cur, pack);
    {
        dim3 gp(300, NLAYERS);
        k_prep<<<gp, 64, 0, stream>>>(mlp_w, ew1, mlp_b, bn_g, bn_b, bn_rm, bn_rv, prm);
    }
    // metal path: mf -> {q, metal2} -> qk  (batched MFMA GEMMs)
    k_mf<<<(1000 * 300 + 255) / 256, 256, 0, stream>>>(mtype, mfeat, me1wT, me1_b, me2, mfb);
    {
        dim3 g1(8, 8);   // M=1024, N=512, K=320
        k_mm<<<g1, 256, 0, stream>>>(mfb, 320, wcat, 320, 320, 0, ml_b, qb, metal2, qk);
        dim3 g2(8, 5);   // M=1024, N=320, K=256
        k_mm<<<g2, 256, 0, stream>>>(qb, 256, wkTb, 256, 256, 1, ml_b, qb, metal2, qk);
    }

    for (int l = 0; l < NLAYERS; ++l) {
        k_gemm<<<784, 256, 0, stream>>>(h, wb + (size_t)l * 102400, mh);
        int aggr_grid = (NNODES + 4 * NPW - 1) / (4 * NPW);
        k_aggr<<<aggr_grid, 256, 0, stream>>>(mh, pack, offs, prm + (size_t)l * 1520, h,
                                              (l < NLAYERS - 1) ? 1 : 0);
    }

    k_pool<<<1000, 320, 0, stream>>>(h, qk, wpb, mnb);
    {
        dim3 ga(8, 4);   // M=1024, N=256, K=320
        k_mm2<<<ga, 256, 0, stream>>>(wpb, 320, wvB, 320, 320, attb, 256);
        k_mm2<<<ga, 256, 0, stream>>>(mnb, 320, lgwB, 320, 320, ligb, 256);
        k_comb<<<(1000 * 256 + 255) / 256, 256, 0, stream>>>(attb, ligb, metal2, lg_b, fb);
        dim3 gph(8, 8);  // M=1024, N=512, K=256
        k_mm2<<<gph, 256, 0, stream>>>(fb, 256, ph1wb, 256, 256, a2, 512);
        k_out<<<1000, 512, 0, stream>>>(a2, ph1_b, ph2_w, ph2_b, (float*)d_out);
    }
}